// Round 8
// baseline (550.726 us; speedup 1.0000x reference)
//
#include <hip/hip_runtime.h>
#include <math.h>

#define NN 10000
#define NE 160000
#define E2 (NE + NN)
#define NG 20
#define MPAD 10112   // 158*64 = 79*128

typedef __attribute__((ext_vector_type(8))) short short8;
typedef __attribute__((ext_vector_type(4))) short short4v;
typedef __attribute__((ext_vector_type(4))) float f32x4;

// ---------- helpers ----------
__device__ inline unsigned short f2bf(float f){
  unsigned u = __float_as_uint(f);
  unsigned r = u + 0x7FFFu + ((u >> 16) & 1u);
  return (unsigned short)(r >> 16);
}
__device__ inline float bf2f(unsigned short h){ return __uint_as_float(((unsigned)h) << 16); }

__device__ inline void gload_lds16(const void* g, void* l){
  __builtin_amdgcn_global_load_lds((const __attribute__((address_space(1))) void*)g,
                                   (__attribute__((address_space(3))) void*)l, 16, 0, 0);
}

// ---------- graph boundary (batch is sorted) ----------
__global__ void k_gptr(const int* __restrict__ batch, int* __restrict__ gptr){
  int g = threadIdx.x;
  if (g > NG) return;
  int lo = 0, hi = NN;
  while (lo < hi){ int mid = (lo+hi)>>1; if (batch[mid] < g) lo = mid+1; else hi = mid; }
  gptr[g] = lo;
}

// ---------- CSR build (by dst, self-loops appended) ----------
__global__ void k_count(const int* __restrict__ ei, int* __restrict__ cnt){
  int e = blockIdx.x*256 + threadIdx.x;
  if (e >= E2) return;
  int d = (e < NE) ? ei[NE + e] : (e - NE);
  atomicAdd(&cnt[d], 1);
}

__global__ void k_scan(const int* __restrict__ cnt, int* __restrict__ ptr){
  __shared__ int tpre[256];
  __shared__ int tsum[256];
  int tid = threadIdx.x;
  const int per = (NN + 255)/256;
  int base = tid*per;
  int s = 0;
  for (int i=0;i<per;i++){ int idx=base+i; if (idx<NN) s += cnt[idx]; }
  tsum[tid] = s;
  __syncthreads();
  if (tid == 0){
    int run = 0;
    for (int i=0;i<256;i++){ tpre[i]=run; run += tsum[i]; }
    ptr[NN] = run;
  }
  __syncthreads();
  int run = tpre[tid];
  for (int i=0;i<per;i++){ int idx=base+i; if (idx<NN){ ptr[idx]=run; run += cnt[idx]; } }
}

__global__ void k_copy(const int* __restrict__ src, int* __restrict__ dst){
  int i = blockIdx.x*256 + threadIdx.x;
  if (i < NN) dst[i] = src[i];
}

__global__ void k_scatter(const int* __restrict__ ei, int* __restrict__ fill, int* __restrict__ csrc){
  int e = blockIdx.x*256 + threadIdx.x;
  if (e >= E2) return;
  int s, d;
  if (e < NE){ s = ei[e]; d = ei[NE + e]; } else { s = d = e - NE; }
  int pos = atomicAdd(&fill[d], 1);
  csrc[pos] = s;
}

// ---------- conversions ----------
__global__ void k_xconv(const float* __restrict__ x, unsigned short* __restrict__ xbf){
  int i = blockIdx.x*256 + threadIdx.x;
  if (i >= MPAD*64) return;
  int r = i >> 6, c = i & 63;
  float v = (r < NN && c < 50) ? x[r*50 + c] : 0.f;
  xbf[i] = f2bf(v);
}

// W: [K][N] row-major f32 -> Wt: [Npad][Kpad] bf16 (transposed, zero-padded)
__global__ void k_wconv(const float* __restrict__ W, unsigned short* __restrict__ Wt,
                        int K, int N, int Kpad, int Npad){
  int i = blockIdx.x*256 + threadIdx.x;
  if (i >= Npad*Kpad) return;
  int nn = i / Kpad, kk = i - nn*Kpad;
  float v = (nn < N && kk < K) ? W[(size_t)kk*N + nn] : 0.f;
  Wt[i] = f2bf(v);
}

// ---------- bf16 MFMA GEMM: C[M,FS] = A[Mpad,K] x Bt[FS,K]^T ----------
// 2-deep counted-vmcnt pipeline (T3+T4), chunk-swizzled LDS, XCD-swizzled grid.
template<int TBM, int TBN>
__global__ __launch_bounds__(256) void k_mfma_gemm(
    const unsigned short* __restrict__ A,
    const unsigned short* __restrict__ Bt,
    unsigned short* __restrict__ Cbf,
    int M, int K, int FS, int ncb)
{
  constexpr int MFR = TBM/32;
  constexpr int NFR = TBN/32;
  constexpr int ABYTES = TBM*64;
  constexpr int BBYTES = TBN*64;
  constexpr int LPS = TBM/64 + TBN/64;   // gload_lds per wave per stage
  __shared__ unsigned short sA[2*TBM*32];
  __shared__ unsigned short sB[2*TBN*32];
  const int tid = threadIdx.x;
  const int wave = tid >> 6;
  const int lane = tid & 63;
  const int nwg = gridDim.x;
  const int q = nwg >> 3, rmod = nwg & 7;
  const int xcd = blockIdx.x & 7, idx = blockIdx.x >> 3;
  const int wg = (xcd < rmod) ? (xcd*(q+1) + idx) : (rmod*(q+1) + (xcd - rmod)*q + idx);
  const int rowt = wg / ncb;
  const int colt = wg - rowt*ncb;
  const int row0 = rowt * TBM;
  const int col0 = colt * TBN;
  const int wr = (wave >> 1) * (TBM/2);
  const int wc = (wave & 1) * (TBN/2);
  f32x4 acc[MFR][NFR];
  #pragma unroll
  for (int i=0;i<MFR;i++)
    #pragma unroll
    for (int j=0;j<NFR;j++){ acc[i][j][0]=0.f; acc[i][j][1]=0.f; acc[i][j][2]=0.f; acc[i][j][3]=0.f; }

  const int arow = tid >> 2;
  const int achn = (tid & 3) ^ ((arow >> 1) & 3);
  const unsigned short* aSrc = A + (size_t)(row0 + arow)*K + achn*8;
  const unsigned short* bSrc = Bt + (size_t)(col0 + arow)*K + achn*8;
  char* ldsA = (char*)sA + wave*1024;
  char* ldsB = (char*)sB + wave*1024;

  auto STAGE = [&](int k0, int buf){
    #pragma unroll
    for (int h=0; h<TBM/64; h++) gload_lds16(aSrc + (size_t)h*64*K + k0, ldsA + buf*ABYTES + h*4096);
    #pragma unroll
    for (int h=0; h<TBN/64; h++) gload_lds16(bSrc + (size_t)h*64*K + k0, ldsB + buf*BBYTES + h*4096);
  };

  const int NT = K >> 5;
  const int kch = lane >> 4;
  const int rlo = lane & 15;

  STAGE(0, 0);
  if (NT > 1) STAGE(32, 1);
  if constexpr (LPS==4)      asm volatile("s_waitcnt vmcnt(4)" ::: "memory");
  else if constexpr (LPS==3) asm volatile("s_waitcnt vmcnt(3)" ::: "memory");
  else                       asm volatile("s_waitcnt vmcnt(2)" ::: "memory");
  __builtin_amdgcn_sched_barrier(0);
  __builtin_amdgcn_s_barrier();

  int cur = 0;
  for (int t = 0; t < NT; ++t){
    const unsigned short* bA = sA + cur*(TBM*32);
    const unsigned short* bB = sB + cur*(TBN*32);
    short8 af[MFR], bfr[NFR];
    #pragma unroll
    for (int m=0;m<MFR;m++){
      int r = wr + m*16 + rlo;
      af[m] = *(const short8*)(bA + r*32 + ((kch ^ ((r>>1)&3))<<3));
    }
    #pragma unroll
    for (int n=0;n<NFR;n++){
      int r = wc + n*16 + rlo;
      bfr[n] = *(const short8*)(bB + r*32 + ((kch ^ ((r>>1)&3))<<3));
    }
    asm volatile("s_waitcnt lgkmcnt(0)" ::: "memory");
    __builtin_amdgcn_sched_barrier(0);
    __builtin_amdgcn_s_barrier();          // all waves done reading buf[cur]
    if (t+2 < NT) STAGE((t+2) << 5, cur);
    #pragma unroll
    for (int m=0;m<MFR;m++)
      #pragma unroll
      for (int n=0;n<NFR;n++)
        acc[m][n] = __builtin_amdgcn_mfma_f32_16x16x32_bf16(af[m], bfr[n], acc[m][n], 0, 0, 0);
    if (t+1 < NT){
      if (t+2 < NT){
        if constexpr (LPS==4)      asm volatile("s_waitcnt vmcnt(4)" ::: "memory");
        else if constexpr (LPS==3) asm volatile("s_waitcnt vmcnt(3)" ::: "memory");
        else                       asm volatile("s_waitcnt vmcnt(2)" ::: "memory");
      } else {
        asm volatile("s_waitcnt vmcnt(0)" ::: "memory");
      }
      __builtin_amdgcn_sched_barrier(0);
      __builtin_amdgcn_s_barrier();
    }
    cur ^= 1;
  }
  const int cr = (lane >> 4) * 4;
  const int cc = lane & 15;
  #pragma unroll
  for (int m=0;m<MFR;m++){
    #pragma unroll
    for (int n=0;n<NFR;n++){
      int col = col0 + wc + n*16 + cc;
      #pragma unroll
      for (int r=0;r<4;r++){
        int row = row0 + wr + m*16 + cr + r;
        if (row < M) Cbf[(size_t)row*FS + col] = f2bf(acc[m][n][r]);
      }
    }
  }
}

// ---------- per-node per-head attention halves (bf16 h, stride FS) ----------
__global__ void k_attprep(const unsigned short* __restrict__ h, const float* __restrict__ atts,
                          const float* __restrict__ attd,
                          float* __restrict__ a_s, float* __restrict__ a_d, int H, int C, int FS){
  int node = blockIdx.x, head = blockIdx.y;
  int lane = threadIdx.x;           // 64
  float ss = 0.f, sd = 0.f;
  if (C == 256){
    const unsigned short* hp = h + (size_t)node*FS + head*256 + lane*4;
    short4v v = *(const short4v*)hp;
    f32x4 sp = *(const f32x4*)(atts + head*256 + lane*4);
    f32x4 dp = *(const f32x4*)(attd + head*256 + lane*4);
    #pragma unroll
    for (int j=0;j<4;j++){ float f = bf2f((unsigned short)v[j]); ss += f*sp[j]; sd += f*dp[j]; }
  } else {
    const unsigned short* hp = h + (size_t)node*FS + head*C;
    const float* sp = atts + head*C;
    const float* dp = attd + head*C;
    for (int c = lane; c < C; c += 64){ float v = bf2f(hp[c]); ss += v*sp[c]; sd += v*dp[c]; }
  }
  #pragma unroll
  for (int o = 32; o; o >>= 1){ ss += __shfl_down(ss, o); sd += __shfl_down(sd, o); }
  if (lane == 0){ a_s[node*H + head] = ss; a_d[node*H + head] = sd; }
}

// ---------- per-node softmax -> alphaT[h][E2] (one wave per node) ----------
__global__ void k_alpha(const float* __restrict__ a_s, const float* __restrict__ a_d,
                        const int* __restrict__ ptr, const int* __restrict__ csrc,
                        float* __restrict__ alphaT, int H, int LH){
  int node = blockIdx.x;
  int lane = threadIdx.x;   // 64
  int beg = ptr[node], deg = ptr[node+1] - beg;
  int items = deg << LH;    // deg*H
  int hh = lane & (H-1);
  float ad = a_d[node*H + hh];
  float mx = -INFINITY;
  for (int i = lane; i < items; i += 64){
    int e = i >> LH;
    int s = csrc[beg + e];
    float ev = a_s[s*H + hh] + ad;
    ev = ev > 0.f ? ev : 0.2f*ev;
    mx = fmaxf(mx, ev);
  }
  for (int o = H; o < 64; o <<= 1) mx = fmaxf(mx, __shfl_xor(mx, o));
  float den = 0.f;
  for (int i = lane; i < items; i += 64){
    int e = i >> LH;
    int s = csrc[beg + e];
    float ev = a_s[s*H + hh] + ad;
    ev = ev > 0.f ? ev : 0.2f*ev;
    den += __expf(ev - mx);
  }
  for (int o = H; o < 64; o <<= 1) den += __shfl_xor(den, o);
  float inv = 1.f / (den + 1e-16f);
  for (int i = lane; i < items; i += 64){
    int e = i >> LH;
    int s = csrc[beg + e];
    float ev = a_s[s*H + hh] + ad;
    ev = ev > 0.f ? ev : 0.2f*ev;
    alphaT[(size_t)hh*E2 + beg + e] = __expf(ev - mx) * inv;
  }
}

// ---------- full-row gather for F=1024,H=4: one block per node ----------
// 128 lanes per edge (whole 2KB h row), 2 edge-groups, 2-edge unroll for MLP.
__global__ __launch_bounds__(256) void k_gather3(
    const unsigned short* __restrict__ h,
    const float* __restrict__ alphaT,
    const int* __restrict__ ptr, const int* __restrict__ csrc,
    const float* __restrict__ bias, float* __restrict__ out)
{
  const int node = blockIdx.x;
  const int beg = ptr[node], deg = ptr[node+1] - beg;
  const int tid = threadIdx.x;
  const int li = tid & 127;
  const int grp = tid >> 7;        // 0/1
  const int head = li >> 5;
  const int c0 = li * 8;
  __shared__ int ssrc[128];
  __shared__ float sal[4][128];
  __shared__ float red[2][1024];
  float acc[8] = {0.f,0.f,0.f,0.f,0.f,0.f,0.f,0.f};
  for (int b0 = 0; b0 < deg; b0 += 128){
    int bn = min(128, deg - b0);
    if (tid < bn){
      ssrc[tid] = csrc[beg + b0 + tid];
      #pragma unroll
      for (int hh=0; hh<4; hh++) sal[hh][tid] = alphaT[(size_t)hh*E2 + beg + b0 + tid];
    }
    __syncthreads();
    int e = grp;
    for (; e + 2 < bn; e += 4){
      int s0 = ssrc[e], s1 = ssrc[e+2];
      float a0 = sal[head][e], a1 = sal[head][e+2];
      short8 v0 = *(const short8*)(h + (size_t)s0*1024 + c0);
      short8 v1 = *(const short8*)(h + (size_t)s1*1024 + c0);
      #pragma unroll
      for (int j=0;j<8;j++) acc[j] += bf2f((unsigned short)v0[j])*a0;
      #pragma unroll
      for (int j=0;j<8;j++) acc[j] += bf2f((unsigned short)v1[j])*a1;
    }
    if (e < bn){
      int s0 = ssrc[e];
      float a0 = sal[head][e];
      short8 v0 = *(const short8*)(h + (size_t)s0*1024 + c0);
      #pragma unroll
      for (int j=0;j<8;j++) acc[j] += bf2f((unsigned short)v0[j])*a0;
    }
    __syncthreads();
  }
  #pragma unroll
  for (int j=0;j<8;j++) red[grp][c0+j] = acc[j];
  __syncthreads();
  #pragma unroll
  for (int k=0;k<4;k++){
    int c = tid + k*256;
    out[(size_t)node*1024 + c] = red[0][c] + red[1][c] + bias[c];
  }
}

// ---------- weighted gather (layer 4): grid (NN,1); L lanes per edge ----------
template<int L>
__global__ __launch_bounds__(256) void k_gather2(
    const unsigned short* __restrict__ h, int FS,
    const float* __restrict__ alphaT,
    const int* __restrict__ ptr, const int* __restrict__ csrc,
    const float* __restrict__ bias, float* __restrict__ out,
    int F, int C, int outF)
{
  constexpr int NGRP = 256 / L;
  constexpr int CS = L * 8;
  const int node = blockIdx.x;
  const int head = blockIdx.y;
  const int colbase = head * C;
  const int beg = ptr[node], deg = ptr[node+1] - beg;
  __shared__ int ssrc[256];
  __shared__ float sal[256];
  __shared__ float red[NGRP * CS];
  const int tid = threadIdx.x;
  const int grp = tid / L, li = tid % L;
  const int c0 = colbase + li*8;
  const float* aT = alphaT + (size_t)head*E2 + beg;
  float acc[8] = {0.f,0.f,0.f,0.f,0.f,0.f,0.f,0.f};
  for (int b0 = 0; b0 < deg; b0 += 256){
    int bn = min(256, deg - b0);
    if (tid < bn){ ssrc[tid] = csrc[beg + b0 + tid]; sal[tid] = aT[b0 + tid]; }
    __syncthreads();
    for (int e = grp; e < bn; e += NGRP){
      int s = ssrc[e];
      float al = sal[e];
      short8 v = *(const short8*)(h + (size_t)s*FS + c0);
      #pragma unroll
      for (int j=0;j<8;j++) acc[j] += bf2f((unsigned short)v[j]) * al;
    }
    __syncthreads();
  }
  #pragma unroll
  for (int j=0;j<8;j++) red[grp*CS + li*8 + j] = acc[j];
  __syncthreads();
  for (int c = tid; c < CS; c += 256){
    float s = 0.f;
    #pragma unroll
    for (int g=0; g<NGRP; g++) s += red[g*CS + c];
    int oc = colbase + c;
    if (oc < F) out[(size_t)node*outF + oc] = s + bias[oc];
  }
}

// ---------- GraphNorm stats / coefs / apply+ELU ----------
#define NSPLIT 16
__global__ void k_gnstats(const float* __restrict__ x, const int* __restrict__ gptr,
                          float* __restrict__ gsum, float* __restrict__ gsq, int F){
  int g = blockIdx.x, cc = blockIdx.y, sp = blockIdx.z;
  int c = cc*256 + threadIdx.x;
  if (c >= F) return;
  int beg = gptr[g], end = gptr[g+1];
  int n = end - beg;
  int per = (n + NSPLIT - 1) / NSPLIT;
  int nb = beg + sp*per, ne = min(end, nb + per);
  if (ne <= nb) return;
  float s = 0.f, q = 0.f;
  for (int i = nb; i < ne; i++){ float v = x[(size_t)i*F + c]; s += v; q += v*v; }
  atomicAdd(&gsum[g*F + c], s);
  atomicAdd(&gsq[g*F + c], q);
}

__global__ void k_coef(const float* __restrict__ gsum, const float* __restrict__ gsq, const int* __restrict__ gptr,
                       const float* __restrict__ w, const float* __restrict__ b, const float* __restrict__ ms,
                       float* __restrict__ cA, float* __restrict__ cB, int F){
  int i = blockIdx.x*256 + threadIdx.x;
  if (i >= NG*F) return;
  int g = i / F, c = i - g*F;
  float cntf = (float)(gptr[g+1] - gptr[g]);
  float m = gsum[i] / cntf;
  float s = ms[c];
  float ex2 = gsq[i] / cntf;
  float var = ex2 - 2.f*s*m*m + s*s*m*m;
  float inv = rsqrtf(var + 1e-5f);
  float wa = w[c]*inv;
  cA[i] = wa;
  cB[i] = b[c] - wa*m*s;
}

__global__ void k_applyelu(const float* __restrict__ x, const int* __restrict__ batch,
                           const float* __restrict__ cA, const float* __restrict__ cB,
                           unsigned short* __restrict__ obf, int F){
  size_t i = (size_t)blockIdx.x*256 + threadIdx.x;
  if (i >= (size_t)NN*F) return;
  int node = (int)(i / F);
  int c = (int)(i - (size_t)node*F);
  int g = batch[node];
  float y = cA[g*F + c]*x[i] + cB[g*F + c];
  y = y > 0.f ? y : expm1f(y);
  obf[i] = f2bf(y);
}

// ---------- orchestration ----------
extern "C" void kernel_launch(void* const* d_in, const int* in_sizes, int n_in,
                              void* d_out, int out_size, void* d_ws, size_t ws_size,
                              hipStream_t stream){
  (void)in_sizes; (void)n_in; (void)out_size; (void)ws_size;
  const float* x     = (const float*)d_in[0];
  const int*   ei    = (const int*)d_in[1];
  const int*   batch = (const int*)d_in[2];
  const float* W[4]  = {(const float*)d_in[3],  (const float*)d_in[7],  (const float*)d_in[11], (const float*)d_in[15]};
  const float* AS[4] = {(const float*)d_in[4],  (const float*)d_in[8],  (const float*)d_in[12], (const float*)d_in[16]};
  const float* AD[4] = {(const float*)d_in[5],  (const float*)d_in[9],  (const float*)d_in[13], (const float*)d_in[17]};
  const float* BI[4] = {(const float*)d_in[6],  (const float*)d_in[10], (const float*)d_in[14], (const float*)d_in[18]};
  const float* GW[3] = {(const float*)d_in[19], (const float*)d_in[22], (const float*)d_in[25]};
  const float* GB[3] = {(const float*)d_in[20], (const float*)d_in[23], (const float*)d_in[26]};
  const float* GA[3] = {(const float*)d_in[21], (const float*)d_in[24], (const float*)d_in[27]};

  float* ws   = (float*)d_ws;
  float* bufB = ws;                                  // [NN,1024] f32
  float* a_s  = bufB + (size_t)NN*1024;              // [NN,4]
  float* a_d  = a_s + (size_t)NN*4;                  // [NN,4]
  float* gsum = a_d + (size_t)NN*4;                  // [NG,1024]
  float* gsq  = gsum + (size_t)NG*1024;              // [NG,1024]
  float* cA   = gsq  + (size_t)NG*1024;              // [NG,1024]
  float* cB   = cA   + (size_t)NG*1024;              // [NG,1024]
  float* alphaT = cB + (size_t)NG*1024;              // [4][E2]
  int* ptr  = (int*)(alphaT + (size_t)4*E2);         // [NN+1]
  int* fill = ptr + (NN + 8);                        // [NN+1]
  int* csrc = fill + (NN + 8);                       // [E2]
  int* gptr = csrc + E2;                             // [NG+1] (pad to 24)
  unsigned short* xbf = (unsigned short*)(gptr + 24);// [MPAD,64] bf16
  unsigned short* abf = xbf + (size_t)MPAD*64;       // [MPAD,1024] bf16
  unsigned short* hbf = abf + (size_t)MPAD*1024;     // [NN,1024] bf16
  unsigned short* Wt  = hbf + (size_t)NN*1024;       // [1024,1024] bf16

  hipMemsetAsync(fill, 0, sizeof(int)*(NN+1), stream);
  k_gptr<<<1, 32, 0, stream>>>(batch, gptr);
  k_count<<<(E2+255)/256, 256, 0, stream>>>(ei, fill);
  k_scan<<<1, 256, 0, stream>>>(fill, ptr);
  k_copy<<<(NN+255)/256, 256, 0, stream>>>(ptr, fill);
  k_scatter<<<(E2+255)/256, 256, 0, stream>>>(ei, fill, csrc);
  k_xconv<<<(MPAD*64+255)/256, 256, 0, stream>>>(x, xbf);

  const int Kp[4]  = {64, 1024, 1024, 1024};
  const int Kr[4]  = {50, 1024, 1024, 1024};
  const int Np[4]  = {1024, 1024, 1024, 128};
  for (int li = 0; li < 4; ++li){
    int H = (li == 3) ? 1 : 4;
    int LH = (li == 3) ? 0 : 2;
    int C = (li == 3) ? 121 : 256;
    int F = H*C;
    int FS = Np[li];
    const unsigned short* Ain = (li == 0) ? xbf : abf;
    k_wconv<<<(Np[li]*Kp[li]+255)/256, 256, 0, stream>>>(W[li], Wt, Kr[li], F, Kp[li], Np[li]);
    if (li < 3){
      int ncb = Np[li]/128;                // 8
      int nwg = (MPAD/64) * ncb;           // 1264
      k_mfma_gemm<64,128><<<nwg, 256, 0, stream>>>(Ain, Wt, hbf, NN, Kp[li], FS, ncb);
    } else {
      int ncb = Np[li]/64;                 // 2
      int nwg = (MPAD/64) * ncb;           // 316
      k_mfma_gemm<64,64><<<nwg, 256, 0, stream>>>(Ain, Wt, hbf, NN, Kp[li], FS, ncb);
    }
    k_attprep<<<dim3(NN, H), 64, 0, stream>>>(hbf, AS[li], AD[li], a_s, a_d, H, C, FS);
    k_alpha<<<NN, 64, 0, stream>>>(a_s, a_d, ptr, csrc, alphaT, H, LH);
    float* gout = (li == 3) ? (float*)d_out : bufB;
    if (li < 3)
      k_gather3<<<NN, 256, 0, stream>>>(hbf, alphaT, ptr, csrc, BI[li], gout);
    else
      k_gather2<16><<<dim3(NN, 1), 256, 0, stream>>>(hbf, FS, alphaT, ptr, csrc, BI[li], gout, F, C, F);
    if (li < 3){
      hipMemsetAsync(gsum, 0, sizeof(float)*2*NG*1024, stream);
      k_gnstats<<<dim3(NG, (F+255)/256, NSPLIT), 256, 0, stream>>>(bufB, gptr, gsum, gsq, F);
      k_coef<<<(NG*F + 255)/256, 256, 0, stream>>>(gsum, gsq, gptr, GW[li], GB[li], GA[li], cA, cB, F);
      size_t tot = (size_t)NN*F;
      k_applyelu<<<(unsigned)((tot + 255)/256), 256, 0, stream>>>(bufB, batch, cA, cB, abf, F);
    }
  }
}

// Round 9
// 518.978 us; speedup vs baseline: 1.0612x; 1.0612x over previous
//
#include <hip/hip_runtime.h>
#include <math.h>

#define NN 10000
#define NE 160000
#define E2 (NE + NN)
#define NG 20
#define MPAD 10112   // 158*64 = 79*128

typedef __attribute__((ext_vector_type(8))) short short8;
typedef __attribute__((ext_vector_type(4))) short short4v;
typedef __attribute__((ext_vector_type(4))) float f32x4;

// ---------- helpers ----------
__device__ inline unsigned short f2bf(float f){
  unsigned u = __float_as_uint(f);
  unsigned r = u + 0x7FFFu + ((u >> 16) & 1u);
  return (unsigned short)(r >> 16);
}
__device__ inline float bf2f(unsigned short h){ return __uint_as_float(((unsigned)h) << 16); }

__device__ inline void gload_lds16(const void* g, void* l){
  __builtin_amdgcn_global_load_lds((const __attribute__((address_space(1))) void*)g,
                                   (__attribute__((address_space(3))) void*)l, 16, 0, 0);
}

// ---------- graph boundary (batch is sorted) ----------
__global__ void k_gptr(const int* __restrict__ batch, int* __restrict__ gptr){
  int g = threadIdx.x;
  if (g > NG) return;
  int lo = 0, hi = NN;
  while (lo < hi){ int mid = (lo+hi)>>1; if (batch[mid] < g) lo = mid+1; else hi = mid; }
  gptr[g] = lo;
}

// ---------- CSR build (by dst, self-loops appended) ----------
__global__ void k_count(const int* __restrict__ ei, int* __restrict__ cnt){
  int e = blockIdx.x*256 + threadIdx.x;
  if (e >= E2) return;
  int d = (e < NE) ? ei[NE + e] : (e - NE);
  atomicAdd(&cnt[d], 1);
}

__global__ void k_scan(const int* __restrict__ cnt, int* __restrict__ ptr){
  __shared__ int tpre[256];
  __shared__ int tsum[256];
  int tid = threadIdx.x;
  const int per = (NN + 255)/256;
  int base = tid*per;
  int s = 0;
  for (int i=0;i<per;i++){ int idx=base+i; if (idx<NN) s += cnt[idx]; }
  tsum[tid] = s;
  __syncthreads();
  if (tid == 0){
    int run = 0;
    for (int i=0;i<256;i++){ tpre[i]=run; run += tsum[i]; }
    ptr[NN] = run;
  }
  __syncthreads();
  int run = tpre[tid];
  for (int i=0;i<per;i++){ int idx=base+i; if (idx<NN){ ptr[idx]=run; run += cnt[idx]; } }
}

__global__ void k_copy(const int* __restrict__ src, int* __restrict__ dst){
  int i = blockIdx.x*256 + threadIdx.x;
  if (i < NN) dst[i] = src[i];
}

__global__ void k_scatter(const int* __restrict__ ei, int* __restrict__ fill, int* __restrict__ csrc){
  int e = blockIdx.x*256 + threadIdx.x;
  if (e >= E2) return;
  int s, d;
  if (e < NE){ s = ei[e]; d = ei[NE + e]; } else { s = d = e - NE; }
  int pos = atomicAdd(&fill[d], 1);
  csrc[pos] = s;
}

// ---------- conversions ----------
__global__ void k_xconv(const float* __restrict__ x, unsigned short* __restrict__ xbf){
  int i = blockIdx.x*256 + threadIdx.x;
  if (i >= MPAD*64) return;
  int r = i >> 6, c = i & 63;
  float v = (r < NN && c < 50) ? x[r*50 + c] : 0.f;
  xbf[i] = f2bf(v);
}

// W: [K][N] row-major f32 -> Wt: [Npad][Kpad] bf16 (transposed, zero-padded)
__global__ void k_wconv(const float* __restrict__ W, unsigned short* __restrict__ Wt,
                        int K, int N, int Kpad, int Npad){
  int i = blockIdx.x*256 + threadIdx.x;
  if (i >= Npad*Kpad) return;
  int nn = i / Kpad, kk = i - nn*Kpad;
  float v = (nn < N && kk < K) ? W[(size_t)kk*N + nn] : 0.f;
  Wt[i] = f2bf(v);
}

// ---------- bf16 MFMA GEMM: C[M,FS] = A[Mpad,K] x Bt[FS,K]^T ----------
// 2-deep counted-vmcnt pipeline, chunk-swizzled LDS, XCD-swizzled grid.
template<int TBM, int TBN>
__global__ __launch_bounds__(256) void k_mfma_gemm(
    const unsigned short* __restrict__ A,
    const unsigned short* __restrict__ Bt,
    unsigned short* __restrict__ Cbf,
    int M, int K, int FS, int ncb)
{
  constexpr int MFR = TBM/32;
  constexpr int NFR = TBN/32;
  constexpr int ABYTES = TBM*64;
  constexpr int BBYTES = TBN*64;
  constexpr int LPS = TBM/64 + TBN/64;
  __shared__ unsigned short sA[2*TBM*32];
  __shared__ unsigned short sB[2*TBN*32];
  const int tid = threadIdx.x;
  const int wave = tid >> 6;
  const int lane = tid & 63;
  const int nwg = gridDim.x;
  const int q = nwg >> 3, rmod = nwg & 7;
  const int xcd = blockIdx.x & 7, idx = blockIdx.x >> 3;
  const int wg = (xcd < rmod) ? (xcd*(q+1) + idx) : (rmod*(q+1) + (xcd - rmod)*q + idx);
  const int rowt = wg / ncb;
  const int colt = wg - rowt*ncb;
  const int row0 = rowt * TBM;
  const int col0 = colt * TBN;
  const int wr = (wave >> 1) * (TBM/2);
  const int wc = (wave & 1) * (TBN/2);
  f32x4 acc[MFR][NFR];
  #pragma unroll
  for (int i=0;i<MFR;i++)
    #pragma unroll
    for (int j=0;j<NFR;j++){ acc[i][j][0]=0.f; acc[i][j][1]=0.f; acc[i][j][2]=0.f; acc[i][j][3]=0.f; }

  const int arow = tid >> 2;
  const int achn = (tid & 3) ^ ((arow >> 1) & 3);
  const unsigned short* aSrc = A + (size_t)(row0 + arow)*K + achn*8;
  const unsigned short* bSrc = Bt + (size_t)(col0 + arow)*K + achn*8;
  char* ldsA = (char*)sA + wave*1024;
  char* ldsB = (char*)sB + wave*1024;

  auto STAGE = [&](int k0, int buf){
    #pragma unroll
    for (int h=0; h<TBM/64; h++) gload_lds16(aSrc + (size_t)h*64*K + k0, ldsA + buf*ABYTES + h*4096);
    #pragma unroll
    for (int h=0; h<TBN/64; h++) gload_lds16(bSrc + (size_t)h*64*K + k0, ldsB + buf*BBYTES + h*4096);
  };

  const int NT = K >> 5;
  const int kch = lane >> 4;
  const int rlo = lane & 15;

  STAGE(0, 0);
  if (NT > 1) STAGE(32, 1);
  if constexpr (LPS==4)      asm volatile("s_waitcnt vmcnt(4)" ::: "memory");
  else if constexpr (LPS==3) asm volatile("s_waitcnt vmcnt(3)" ::: "memory");
  else                       asm volatile("s_waitcnt vmcnt(2)" ::: "memory");
  __builtin_amdgcn_sched_barrier(0);
  __builtin_amdgcn_s_barrier();

  int cur = 0;
  for (int t = 0; t < NT; ++t){
    const unsigned short* bA = sA + cur*(TBM*32);
    const unsigned short* bB = sB + cur*(TBN*32);
    short8 af[MFR], bfr[NFR];
    #pragma unroll
    for (int m=0;m<MFR;m++){
      int r = wr + m*16 + rlo;
      af[m] = *(const short8*)(bA + r*32 + ((kch ^ ((r>>1)&3))<<3));
    }
    #pragma unroll
    for (int n=0;n<NFR;n++){
      int r = wc + n*16 + rlo;
      bfr[n] = *(const short8*)(bB + r*32 + ((kch ^ ((r>>1)&3))<<3));
    }
    asm volatile("s_waitcnt lgkmcnt(0)" ::: "memory");
    __builtin_amdgcn_sched_barrier(0);
    __builtin_amdgcn_s_barrier();
    if (t+2 < NT) STAGE((t+2) << 5, cur);
    #pragma unroll
    for (int m=0;m<MFR;m++)
      #pragma unroll
      for (int n=0;n<NFR;n++)
        acc[m][n] = __builtin_amdgcn_mfma_f32_16x16x32_bf16(af[m], bfr[n], acc[m][n], 0, 0, 0);
    if (t+1 < NT){
      if (t+2 < NT){
        if constexpr (LPS==4)      asm volatile("s_waitcnt vmcnt(4)" ::: "memory");
        else if constexpr (LPS==3) asm volatile("s_waitcnt vmcnt(3)" ::: "memory");
        else                       asm volatile("s_waitcnt vmcnt(2)" ::: "memory");
      } else {
        asm volatile("s_waitcnt vmcnt(0)" ::: "memory");
      }
      __builtin_amdgcn_sched_barrier(0);
      __builtin_amdgcn_s_barrier();
    }
    cur ^= 1;
  }
  const int cr = (lane >> 4) * 4;
  const int cc = lane & 15;
  #pragma unroll
  for (int m=0;m<MFR;m++){
    #pragma unroll
    for (int n=0;n<NFR;n++){
      int col = col0 + wc + n*16 + cc;
      #pragma unroll
      for (int r=0;r<4;r++){
        int row = row0 + wr + m*16 + cr + r;
        if (row < M) Cbf[(size_t)row*FS + col] = f2bf(acc[m][n][r]);
      }
    }
  }
}

// ---------- wave-per-node attention halves (F=1024, H=4, FS=1024) ----------
__global__ __launch_bounds__(256) void k_attprepw(
    const unsigned short* __restrict__ h,
    const float* __restrict__ atts, const float* __restrict__ attd,
    float* __restrict__ a_s, float* __restrict__ a_d)
{
  const int wid = threadIdx.x >> 6, lane = threadIdx.x & 63;
  const int node = blockIdx.x*4 + wid;
  const unsigned short* hp = h + (size_t)node*1024 + lane*16;
  short8 v0 = *(const short8*)hp;
  short8 v1 = *(const short8*)(hp+8);
  const float* sp = atts + lane*16;
  const float* dp = attd + lane*16;
  float ss = 0.f, sd = 0.f;
  #pragma unroll
  for (int j=0;j<8;j++){ float f = bf2f((unsigned short)v0[j]); ss += f*sp[j];   sd += f*dp[j]; }
  #pragma unroll
  for (int j=0;j<8;j++){ float f = bf2f((unsigned short)v1[j]); ss += f*sp[8+j]; sd += f*dp[8+j]; }
  #pragma unroll
  for (int o=8;o;o>>=1){ ss += __shfl_xor(ss,o); sd += __shfl_xor(sd,o); }
  if ((lane & 15) == 0){
    int hh = lane >> 4;
    a_s[node*4 + hh] = ss;
    a_d[node*4 + hh] = sd;
  }
}

// ---------- old attprep (layer 4, C=121) ----------
__global__ void k_attprep(const unsigned short* __restrict__ h, const float* __restrict__ atts,
                          const float* __restrict__ attd,
                          float* __restrict__ a_s, float* __restrict__ a_d, int H, int C, int FS){
  int node = blockIdx.x, head = blockIdx.y;
  int lane = threadIdx.x;
  const unsigned short* hp = h + (size_t)node*FS + head*C;
  const float* sp = atts + head*C;
  const float* dp = attd + head*C;
  float ss = 0.f, sd = 0.f;
  for (int c = lane; c < C; c += 64){ float v = bf2f(hp[c]); ss += v*sp[c]; sd += v*dp[c]; }
  #pragma unroll
  for (int o = 32; o; o >>= 1){ ss += __shfl_down(ss, o); sd += __shfl_down(sd, o); }
  if (lane == 0){ a_s[node*H + head] = ss; a_d[node*H + head] = sd; }
}

// ---------- per-node softmax -> alphaT (layer 4 only, H=1) ----------
__global__ void k_alpha(const float* __restrict__ a_s, const float* __restrict__ a_d,
                        const int* __restrict__ ptr, const int* __restrict__ csrc,
                        float* __restrict__ alphaT, int H, int LH){
  int node = blockIdx.x;
  int lane = threadIdx.x;
  int beg = ptr[node], deg = ptr[node+1] - beg;
  int items = deg << LH;
  int hh = lane & (H-1);
  float ad = a_d[node*H + hh];
  float mx = -INFINITY;
  for (int i = lane; i < items; i += 64){
    int e = i >> LH;
    int s = csrc[beg + e];
    float ev = a_s[s*H + hh] + ad;
    ev = ev > 0.f ? ev : 0.2f*ev;
    mx = fmaxf(mx, ev);
  }
  for (int o = H; o < 64; o <<= 1) mx = fmaxf(mx, __shfl_xor(mx, o));
  float den = 0.f;
  for (int i = lane; i < items; i += 64){
    int e = i >> LH;
    int s = csrc[beg + e];
    float ev = a_s[s*H + hh] + ad;
    ev = ev > 0.f ? ev : 0.2f*ev;
    den += __expf(ev - mx);
  }
  for (int o = H; o < 64; o <<= 1) den += __shfl_xor(den, o);
  float inv = 1.f / (den + 1e-16f);
  for (int i = lane; i < items; i += 64){
    int e = i >> LH;
    int s = csrc[beg + e];
    float ev = a_s[s*H + hh] + ad;
    ev = ev > 0.f ? ev : 0.2f*ev;
    alphaT[(size_t)hh*E2 + beg + e] = __expf(ev - mx) * inv;
  }
}

// ---------- fused softmax + gather, wave-per-node (F=1024, H=4, FS=1024) ----------
// Softmax without max-subtraction (scale-invariant; |e| << 88 here). One wave
// owns one node: lane e stages exp(e)/src to its wave's LDS slice; all lanes
// then gather 32B/lane of each source row with dual-accumulator pairwise loop.
__global__ __launch_bounds__(256) void k_gatherw(
    const unsigned short* __restrict__ h,
    const float* __restrict__ a_s, const float* __restrict__ a_d,
    const int* __restrict__ ptr, const int* __restrict__ csrc,
    const float* __restrict__ bias, float* __restrict__ out)
{
  __shared__ float sal[4][64*4];
  __shared__ int ssn[4][64];
  const int wid = threadIdx.x >> 6, lane = threadIdx.x & 63;
  const int node = blockIdx.x*4 + wid;
  const int hh = lane >> 4;                 // head of this lane's 16 channels
  const int beg = ptr[node], deg = ptr[node+1] - beg;
  f32x4 ad4 = *(const f32x4*)(a_d + node*4);
  float acc[16], acc2[16];
  #pragma unroll
  for (int j=0;j<16;j++){ acc[j]=0.f; acc2[j]=0.f; }
  f32x4 denp = {0.f,0.f,0.f,0.f};
  const unsigned short* hb = h + lane*16;

  for (int c0 = 0; c0 < deg; c0 += 64){
    int n = min(64, deg - c0);
    if (lane < n){
      int s = csrc[beg + c0 + lane];
      f32x4 as4 = *(const f32x4*)(a_s + s*4);
      f32x4 e4;
      #pragma unroll
      for (int k2=0;k2<4;k2++){
        float ev = as4[k2] + ad4[k2];
        ev = ev > 0.f ? ev : 0.2f*ev;
        float x = __expf(ev);
        e4[k2] = x;
        denp[k2] += x;
      }
      *(f32x4*)&sal[wid][lane*4] = e4;
      ssn[wid][lane] = s;
    }
    int e = 0;
    for (; e + 1 < n; e += 2){
      int sA_ = ssn[wid][e], sB_ = ssn[wid][e+1];
      float aA = sal[wid][e*4 + hh], aB = sal[wid][(e+1)*4 + hh];
      const unsigned short* pA = hb + (size_t)sA_*1024;
      const unsigned short* pB = hb + (size_t)sB_*1024;
      short8 uA0 = *(const short8*)pA, uA1 = *(const short8*)(pA+8);
      short8 uB0 = *(const short8*)pB, uB1 = *(const short8*)(pB+8);
      #pragma unroll
      for (int j=0;j<8;j++){ acc[j]   += bf2f((unsigned short)uA0[j])*aA;
                             acc[8+j] += bf2f((unsigned short)uA1[j])*aA; }
      #pragma unroll
      for (int j=0;j<8;j++){ acc2[j]   += bf2f((unsigned short)uB0[j])*aB;
                             acc2[8+j] += bf2f((unsigned short)uB1[j])*aB; }
    }
    if (e < n){
      int sA_ = ssn[wid][e];
      float aA = sal[wid][e*4 + hh];
      const unsigned short* pA = hb + (size_t)sA_*1024;
      short8 uA0 = *(const short8*)pA, uA1 = *(const short8*)(pA+8);
      #pragma unroll
      for (int j=0;j<8;j++){ acc[j]   += bf2f((unsigned short)uA0[j])*aA;
                             acc[8+j] += bf2f((unsigned short)uA1[j])*aA; }
    }
  }
  // wave-sum of denom per head component
  #pragma unroll
  for (int o=32;o;o>>=1){
    #pragma unroll
    for (int k2=0;k2<4;k2++) denp[k2] += __shfl_xor(denp[k2], o);
  }
  float inv = 1.f / (denp[hh] + 1e-16f);
  float* op = out + (size_t)node*1024 + lane*16;
  const float* bp = bias + lane*16;
  #pragma unroll
  for (int j=0;j<16;j++) op[j] = (acc[j]+acc2[j])*inv + bp[j];
}

// ---------- weighted gather (layer 4): grid (NN,1); L lanes per edge ----------
template<int L>
__global__ __launch_bounds__(256) void k_gather2(
    const unsigned short* __restrict__ h, int FS,
    const float* __restrict__ alphaT,
    const int* __restrict__ ptr, const int* __restrict__ csrc,
    const float* __restrict__ bias, float* __restrict__ out,
    int F, int C, int outF)
{
  constexpr int NGRP = 256 / L;
  constexpr int CS = L * 8;
  const int node = blockIdx.x;
  const int head = blockIdx.y;
  const int colbase = head * C;
  const int beg = ptr[node], deg = ptr[node+1] - beg;
  __shared__ int ssrc[256];
  __shared__ float salv[256];
  __shared__ float red[NGRP * CS];
  const int tid = threadIdx.x;
  const int grp = tid / L, li = tid % L;
  const int c0 = colbase + li*8;
  const float* aT = alphaT + (size_t)head*E2 + beg;
  float acc[8] = {0.f,0.f,0.f,0.f,0.f,0.f,0.f,0.f};
  for (int b0 = 0; b0 < deg; b0 += 256){
    int bn = min(256, deg - b0);
    if (tid < bn){ ssrc[tid] = csrc[beg + b0 + tid]; salv[tid] = aT[b0 + tid]; }
    __syncthreads();
    for (int e = grp; e < bn; e += NGRP){
      int s = ssrc[e];
      float al = salv[e];
      short8 v = *(const short8*)(h + (size_t)s*FS + c0);
      #pragma unroll
      for (int j=0;j<8;j++) acc[j] += bf2f((unsigned short)v[j]) * al;
    }
    __syncthreads();
  }
  #pragma unroll
  for (int j=0;j<8;j++) red[grp*CS + li*8 + j] = acc[j];
  __syncthreads();
  for (int c = tid; c < CS; c += 256){
    float s = 0.f;
    #pragma unroll
    for (int g=0; g<NGRP; g++) s += red[g*CS + c];
    int oc = colbase + c;
    if (oc < F) out[(size_t)node*outF + oc] = s + bias[oc];
  }
}

// ---------- GraphNorm stats / coefs / apply+ELU ----------
#define NSPLIT 16
__global__ void k_gnstats(const float* __restrict__ x, const int* __restrict__ gptr,
                          float* __restrict__ gsum, float* __restrict__ gsq, int F){
  int g = blockIdx.x, cc = blockIdx.y, sp = blockIdx.z;
  int c = cc*256 + threadIdx.x;
  if (c >= F) return;
  int beg = gptr[g], end = gptr[g+1];
  int n = end - beg;
  int per = (n + NSPLIT - 1) / NSPLIT;
  int nb = beg + sp*per, ne = min(end, nb + per);
  if (ne <= nb) return;
  float s = 0.f, q = 0.f;
  for (int i = nb; i < ne; i++){ float v = x[(size_t)i*F + c]; s += v; q += v*v; }
  atomicAdd(&gsum[g*F + c], s);
  atomicAdd(&gsq[g*F + c], q);
}

__global__ void k_coef(const float* __restrict__ gsum, const float* __restrict__ gsq, const int* __restrict__ gptr,
                       const float* __restrict__ w, const float* __restrict__ b, const float* __restrict__ ms,
                       float* __restrict__ cA, float* __restrict__ cB, int F){
  int i = blockIdx.x*256 + threadIdx.x;
  if (i >= NG*F) return;
  int g = i / F, c = i - g*F;
  float cntf = (float)(gptr[g+1] - gptr[g]);
  float m = gsum[i] / cntf;
  float s = ms[c];
  float ex2 = gsq[i] / cntf;
  float var = ex2 - 2.f*s*m*m + s*s*m*m;
  float inv = rsqrtf(var + 1e-5f);
  float wa = w[c]*inv;
  cA[i] = wa;
  cB[i] = b[c] - wa*m*s;
}

__global__ void k_applyelu(const float* __restrict__ x, const int* __restrict__ batch,
                           const float* __restrict__ cA, const float* __restrict__ cB,
                           unsigned short* __restrict__ obf, int F){
  size_t i = (size_t)blockIdx.x*256 + threadIdx.x;
  if (i >= (size_t)NN*F) return;
  int node = (int)(i / F);
  int c = (int)(i - (size_t)node*F);
  int g = batch[node];
  float y = cA[g*F + c]*x[i] + cB[g*F + c];
  y = y > 0.f ? y : expm1f(y);
  obf[i] = f2bf(y);
}

// ---------- orchestration ----------
extern "C" void kernel_launch(void* const* d_in, const int* in_sizes, int n_in,
                              void* d_out, int out_size, void* d_ws, size_t ws_size,
                              hipStream_t stream){
  (void)in_sizes; (void)n_in; (void)out_size; (void)ws_size;
  const float* x     = (const float*)d_in[0];
  const int*   ei    = (const int*)d_in[1];
  const int*   batch = (const int*)d_in[2];
  const float* W[4]  = {(const float*)d_in[3],  (const float*)d_in[7],  (const float*)d_in[11], (const float*)d_in[15]};
  const float* AS[4] = {(const float*)d_in[4],  (const float*)d_in[8],  (const float*)d_in[12], (const float*)d_in[16]};
  const float* AD[4] = {(const float*)d_in[5],  (const float*)d_in[9],  (const float*)d_in[13], (const float*)d_in[17]};
  const float* BI[4] = {(const float*)d_in[6],  (const float*)d_in[10], (const float*)d_in[14], (const float*)d_in[18]};
  const float* GW[3] = {(const float*)d_in[19], (const float*)d_in[22], (const float*)d_in[25]};
  const float* GB[3] = {(const float*)d_in[20], (const float*)d_in[23], (const float*)d_in[26]};
  const float* GA[3] = {(const float*)d_in[21], (const float*)d_in[24], (const float*)d_in[27]};

  float* ws   = (float*)d_ws;
  float* bufB = ws;                                  // [NN,1024] f32
  float* a_s  = bufB + (size_t)NN*1024;              // [NN,4]
  float* a_d  = a_s + (size_t)NN*4;                  // [NN,4]
  float* gsum = a_d + (size_t)NN*4;                  // [NG,1024]
  float* gsq  = gsum + (size_t)NG*1024;              // [NG,1024]
  float* cA   = gsq  + (size_t)NG*1024;              // [NG,1024]
  float* cB   = cA   + (size_t)NG*1024;              // [NG,1024]
  float* alphaT = cB + (size_t)NG*1024;              // [4][E2] (L4 only)
  int* ptr  = (int*)(alphaT + (size_t)4*E2);         // [NN+1]
  int* fill = ptr + (NN + 8);                        // [NN+1]
  int* csrc = fill + (NN + 8);                       // [E2]
  int* gptr = csrc + E2;                             // [NG+1] (pad to 24)
  unsigned short* xbf = (unsigned short*)(gptr + 24);// [MPAD,64] bf16
  unsigned short* abf = xbf + (size_t)MPAD*64;       // [MPAD,1024] bf16
  unsigned short* hbf = abf + (size_t)MPAD*1024;     // [NN,1024] bf16
  unsigned short* Wt  = hbf + (size_t)NN*1024;       // [1024,1024] bf16

  hipMemsetAsync(fill, 0, sizeof(int)*(NN+1), stream);
  k_gptr<<<1, 32, 0, stream>>>(batch, gptr);
  k_count<<<(E2+255)/256, 256, 0, stream>>>(ei, fill);
  k_scan<<<1, 256, 0, stream>>>(fill, ptr);
  k_copy<<<(NN+255)/256, 256, 0, stream>>>(ptr, fill);
  k_scatter<<<(E2+255)/256, 256, 0, stream>>>(ei, fill, csrc);
  k_xconv<<<(MPAD*64+255)/256, 256, 0, stream>>>(x, xbf);

  const int Kp[4]  = {64, 1024, 1024, 1024};
  const int Kr[4]  = {50, 1024, 1024, 1024};
  const int Np[4]  = {1024, 1024, 1024, 128};
  for (int li = 0; li < 4; ++li){
    int H = (li == 3) ? 1 : 4;
    int LH = (li == 3) ? 0 : 2;
    int C = (li == 3) ? 121 : 256;
    int F = H*C;
    int FS = Np[li];
    const unsigned short* Ain = (li == 0) ? xbf : abf;
    k_wconv<<<(Np[li]*Kp[li]+255)/256, 256, 0, stream>>>(W[li], Wt, Kr[li], F, Kp[li], Np[li]);
    if (li < 3){
      int ncb = Np[li]/128;                // 8
      int nwg = (MPAD/64) * ncb;           // 1264
      k_mfma_gemm<64,128><<<nwg, 256, 0, stream>>>(Ain, Wt, hbf, NN, Kp[li], FS, ncb);
      k_attprepw<<<NN/4, 256, 0, stream>>>(hbf, AS[li], AD[li], a_s, a_d);
      k_gatherw<<<NN/4, 256, 0, stream>>>(hbf, a_s, a_d, ptr, csrc, BI[li], bufB);
      hipMemsetAsync(gsum, 0, sizeof(float)*2*NG*1024, stream);
      k_gnstats<<<dim3(NG, (F+255)/256, NSPLIT), 256, 0, stream>>>(bufB, gptr, gsum, gsq, F);
      k_coef<<<(NG*F + 255)/256, 256, 0, stream>>>(gsum, gsq, gptr, GW[li], GB[li], GA[li], cA, cB, F);
      size_t tot = (size_t)NN*F;
      k_applyelu<<<(unsigned)((tot + 255)/256), 256, 0, stream>>>(bufB, batch, cA, cB, abf, F);
    } else {
      int ncb = Np[li]/64;                 // 2
      int nwg = (MPAD/64) * ncb;           // 316
      k_mfma_gemm<64,64><<<nwg, 256, 0, stream>>>(Ain, Wt, hbf, NN, Kp[li], FS, ncb);
      k_attprep<<<dim3(NN, 1), 64, 0, stream>>>(hbf, AS[li], AD[li], a_s, a_d, H, C, FS);
      k_alpha<<<NN, 64, 0, stream>>>(a_s, a_d, ptr, csrc, alphaT, H, LH);
      k_gather2<16><<<dim3(NN, 1), 256, 0, stream>>>(hbf, FS, alphaT, ptr, csrc, BI[li], (float*)d_out, F, C, F);
    }
  }
}

// Round 10
// 516.242 us; speedup vs baseline: 1.0668x; 1.0053x over previous
//
#include <hip/hip_runtime.h>
#include <math.h>

#define NN 10000
#define NE 160000
#define E2 (NE + NN)
#define NG 20
#define MPAD 10112   // 158*64 = 79*128
#define NSPLIT 8

typedef __attribute__((ext_vector_type(8))) short short8;
typedef __attribute__((ext_vector_type(4))) float f32x4;

// ---------- helpers ----------
__device__ inline unsigned short f2bf(float f){
  unsigned u = __float_as_uint(f);
  unsigned r = u + 0x7FFFu + ((u >> 16) & 1u);
  return (unsigned short)(r >> 16);
}
__device__ inline float bf2f(unsigned short h){ return __uint_as_float(((unsigned)h) << 16); }

__device__ inline void gload_lds16(const void* g, void* l){
  __builtin_amdgcn_global_load_lds((const __attribute__((address_space(1))) void*)g,
                                   (__attribute__((address_space(3))) void*)l, 16, 0, 0);
}

// ---------- graph boundary (batch is sorted) ----------
__global__ void k_gptr(const int* __restrict__ batch, int* __restrict__ gptr){
  int g = threadIdx.x;
  if (g > NG) return;
  int lo = 0, hi = NN;
  while (lo < hi){ int mid = (lo+hi)>>1; if (batch[mid] < g) lo = mid+1; else hi = mid; }
  gptr[g] = lo;
}

// ---------- CSR build (by dst, self-loops appended) ----------
__global__ void k_count(const int* __restrict__ ei, int* __restrict__ cnt){
  int e = blockIdx.x*256 + threadIdx.x;
  if (e >= E2) return;
  int d = (e < NE) ? ei[NE + e] : (e - NE);
  atomicAdd(&cnt[d], 1);
}

__global__ void k_scan(const int* __restrict__ cnt, int* __restrict__ ptr){
  __shared__ int tpre[256];
  __shared__ int tsum[256];
  int tid = threadIdx.x;
  const int per = (NN + 255)/256;
  int base = tid*per;
  int s = 0;
  for (int i=0;i<per;i++){ int idx=base+i; if (idx<NN) s += cnt[idx]; }
  tsum[tid] = s;
  __syncthreads();
  if (tid == 0){
    int run = 0;
    for (int i=0;i<256;i++){ tpre[i]=run; run += tsum[i]; }
    ptr[NN] = run;
  }
  __syncthreads();
  int run = tpre[tid];
  for (int i=0;i<per;i++){ int idx=base+i; if (idx<NN){ ptr[idx]=run; run += cnt[idx]; } }
}

__global__ void k_copy(const int* __restrict__ src, int* __restrict__ dst){
  int i = blockIdx.x*256 + threadIdx.x;
  if (i < NN) dst[i] = src[i];
}

__global__ void k_scatter(const int* __restrict__ ei, int* __restrict__ fill, int* __restrict__ csrc){
  int e = blockIdx.x*256 + threadIdx.x;
  if (e >= E2) return;
  int s, d;
  if (e < NE){ s = ei[e]; d = ei[NE + e]; } else { s = d = e - NE; }
  int pos = atomicAdd(&fill[d], 1);
  csrc[pos] = s;
}

// ---------- conversions ----------
__global__ void k_xconv(const float* __restrict__ x, unsigned short* __restrict__ xbf){
  int i = blockIdx.x*256 + threadIdx.x;
  if (i >= MPAD*64) return;
  int r = i >> 6, c = i & 63;
  float v = (r < NN && c < 50) ? x[r*50 + c] : 0.f;
  xbf[i] = f2bf(v);
}

// all four W -> transposed bf16 (zero-padded), single kernel
#define WT0 0
#define WT1 65536
#define WT2 1114112
#define WT3 2162688
#define WTT 2293760
__global__ void k_wconvall(const float* __restrict__ W0, const float* __restrict__ W1,
                           const float* __restrict__ W2, const float* __restrict__ W3,
                           unsigned short* __restrict__ wt){
  int i = blockIdx.x*256 + threadIdx.x;
  if (i >= WTT) return;
  const float* W; int K, N, Kpad, off;
  if (i < WT1){ W=W0; K=50; N=1024; Kpad=64; off=WT0; }
  else if (i < WT2){ W=W1; K=1024; N=1024; Kpad=1024; off=WT1; }
  else if (i < WT3){ W=W2; K=1024; N=1024; Kpad=1024; off=WT2; }
  else { W=W3; K=1024; N=121; Kpad=1024; off=WT3; }
  int j = i - off;
  int nn = j / Kpad, kk = j - nn*Kpad;
  float v = (nn < N && kk < K) ? W[(size_t)kk*N + nn] : 0.f;
  wt[i] = f2bf(v);
}

// ---------- bf16 MFMA GEMM: C[M,FS] = A[Mpad,K] x Bt[FS,K]^T ----------
// 3-buffer LDS, ONE barrier per K-step, counted vmcnt (2-iteration load cover),
// compiler-managed lgkmcnt between ds_read and MFMA, chunk swizzle, XCD swizzle.
template<int TBM, int TBN>
__global__ __launch_bounds__(256) void k_mfma_gemm(
    const unsigned short* __restrict__ A,
    const unsigned short* __restrict__ Bt,
    unsigned short* __restrict__ Cbf,
    int M, int K, int FS, int ncb)
{
  constexpr int MFR = TBM/32;
  constexpr int NFR = TBN/32;
  constexpr int ABYTES = TBM*64;
  constexpr int BBYTES = TBN*64;
  constexpr int LPS = TBM/64 + TBN/64;   // VMEM insts per wave per stage
  __shared__ unsigned short sA[3*TBM*32];
  __shared__ unsigned short sB[3*TBN*32];
  const int tid = threadIdx.x;
  const int wave = tid >> 6;
  const int lane = tid & 63;
  const int nwg = gridDim.x;
  const int q = nwg >> 3, rmod = nwg & 7;
  const int xcd = blockIdx.x & 7, idx = blockIdx.x >> 3;
  const int wg = (xcd < rmod) ? (xcd*(q+1) + idx) : (rmod*(q+1) + (xcd - rmod)*q + idx);
  const int rowt = wg / ncb;
  const int colt = wg - rowt*ncb;
  const int row0 = rowt * TBM;
  const int col0 = colt * TBN;
  const int wr = (wave >> 1) * (TBM/2);
  const int wc = (wave & 1) * (TBN/2);
  f32x4 acc[MFR][NFR];
  #pragma unroll
  for (int i=0;i<MFR;i++)
    #pragma unroll
    for (int j=0;j<NFR;j++){ acc[i][j][0]=0.f; acc[i][j][1]=0.f; acc[i][j][2]=0.f; acc[i][j][3]=0.f; }

  const int arow = tid >> 2;
  const int achn = (tid & 3) ^ ((arow >> 1) & 3);
  const unsigned short* aSrc = A + (size_t)(row0 + arow)*K + achn*8;
  const unsigned short* bSrc = Bt + (size_t)(col0 + arow)*K + achn*8;
  char* ldsA = (char*)sA + wave*1024;
  char* ldsB = (char*)sB + wave*1024;

  auto STAGE = [&](int k0, int buf){
    #pragma unroll
    for (int h=0; h<TBM/64; h++) gload_lds16(aSrc + (size_t)h*64*K + k0, ldsA + buf*ABYTES + h*4096);
    #pragma unroll
    for (int h=0; h<TBN/64; h++) gload_lds16(bSrc + (size_t)h*64*K + k0, ldsB + buf*BBYTES + h*4096);
  };

  const int NT = K >> 5;     // >= 2 always (K >= 64)
  const int kch = lane >> 4;
  const int rlo = lane & 15;

  STAGE(0, 0);
  STAGE(32, 1);

  int cur = 0;
  for (int t = 0; t < NT; ++t){
    asm volatile("s_waitcnt lgkmcnt(0)" ::: "memory");   // free; pins prior LDS reads above
    if (t+1 < NT){
      if constexpr (LPS==4)      asm volatile("s_waitcnt vmcnt(4)" ::: "memory");
      else if constexpr (LPS==3) asm volatile("s_waitcnt vmcnt(3)" ::: "memory");
      else                       asm volatile("s_waitcnt vmcnt(2)" ::: "memory");
    } else {
      asm volatile("s_waitcnt vmcnt(0)" ::: "memory");
    }
    __builtin_amdgcn_sched_barrier(0);
    __builtin_amdgcn_s_barrier();        // all waves' tile-t loads complete
    __builtin_amdgcn_sched_barrier(0);
    const unsigned short* bA = sA + cur*(TBM*32);
    const unsigned short* bB = sB + cur*(TBN*32);
    short8 af[MFR], bfr[NFR];
    #pragma unroll
    for (int m=0;m<MFR;m++){
      int r = wr + m*16 + rlo;
      af[m] = *(const short8*)(bA + r*32 + ((kch ^ ((r>>1)&3))<<3));
    }
    #pragma unroll
    for (int n=0;n<NFR;n++){
      int r = wc + n*16 + rlo;
      bfr[n] = *(const short8*)(bB + r*32 + ((kch ^ ((r>>1)&3))<<3));
    }
    if (t+2 < NT){
      int nb = cur + 2; if (nb >= 3) nb -= 3;
      STAGE((t+2) << 5, nb);             // never touches buf being read (t) or next (t+1)
    }
    __builtin_amdgcn_s_setprio(1);
    #pragma unroll
    for (int m=0;m<MFR;m++)
      #pragma unroll
      for (int n=0;n<NFR;n++)
        acc[m][n] = __builtin_amdgcn_mfma_f32_16x16x32_bf16(af[m], bfr[n], acc[m][n], 0, 0, 0);
    __builtin_amdgcn_s_setprio(0);
    cur += 1; if (cur == 3) cur = 0;
  }
  const int cr = (lane >> 4) * 4;
  const int cc = lane & 15;
  #pragma unroll
  for (int m=0;m<MFR;m++){
    #pragma unroll
    for (int n=0;n<NFR;n++){
      int col = col0 + wc + n*16 + cc;
      #pragma unroll
      for (int r=0;r<4;r++){
        int row = row0 + wr + m*16 + cr + r;
        if (row < M) Cbf[(size_t)row*FS + col] = f2bf(acc[m][n][r]);
      }
    }
  }
}

// ---------- wave-per-node attention halves (F=1024, H=4, FS=1024) ----------
__global__ __launch_bounds__(256) void k_attprepw(
    const unsigned short* __restrict__ h,
    const float* __restrict__ atts, const float* __restrict__ attd,
    float* __restrict__ a_s, float* __restrict__ a_d)
{
  const int wid = threadIdx.x >> 6, lane = threadIdx.x & 63;
  const int node = blockIdx.x*4 + wid;
  const unsigned short* hp = h + (size_t)node*1024 + lane*16;
  short8 v0 = *(const short8*)hp;
  short8 v1 = *(const short8*)(hp+8);
  const float* sp = atts + lane*16;
  const float* dp = attd + lane*16;
  float ss = 0.f, sd = 0.f;
  #pragma unroll
  for (int j=0;j<8;j++){ float f = bf2f((unsigned short)v0[j]); ss += f*sp[j];   sd += f*dp[j]; }
  #pragma unroll
  for (int j=0;j<8;j++){ float f = bf2f((unsigned short)v1[j]); ss += f*sp[8+j]; sd += f*dp[8+j]; }
  #pragma unroll
  for (int o=8;o;o>>=1){ ss += __shfl_xor(ss,o); sd += __shfl_xor(sd,o); }
  if ((lane & 15) == 0){
    int hh = lane >> 4;
    a_s[node*4 + hh] = ss;
    a_d[node*4 + hh] = sd;
  }
}

// ---------- wave-per-node attention halves (layer 4: F=121, FS=128, H=1) ----------
__global__ __launch_bounds__(256) void k_attprep4(
    const unsigned short* __restrict__ h,
    const float* __restrict__ atts, const float* __restrict__ attd,
    float* __restrict__ a_s, float* __restrict__ a_d)
{
  const int wid = threadIdx.x >> 6, lane = threadIdx.x & 63;
  const int node = blockIdx.x*4 + wid;
  const unsigned short* hp = h + (size_t)node*128;
  float ss = 0.f, sd = 0.f;
  {
    float f = bf2f(hp[lane]);
    if (lane < 121){ ss += f*atts[lane]; sd += f*attd[lane]; }
  }
  int c2 = lane + 64;
  if (c2 < 121){
    float f = bf2f(hp[c2]);
    ss += f*atts[c2]; sd += f*attd[c2];
  }
  #pragma unroll
  for (int o=32;o;o>>=1){ ss += __shfl_xor(ss,o); sd += __shfl_xor(sd,o); }
  if (lane == 0){ a_s[node] = ss; a_d[node] = sd; }
}

// ---------- fused softmax + gather, wave-per-node (F=1024, H=4, FS=1024) ----------
__global__ __launch_bounds__(256) void k_gatherw(
    const unsigned short* __restrict__ h,
    const float* __restrict__ a_s, const float* __restrict__ a_d,
    const int* __restrict__ ptr, const int* __restrict__ csrc,
    const float* __restrict__ bias, float* __restrict__ out)
{
  __shared__ float sal[4][64*4];
  __shared__ int ssn[4][64];
  const int wid = threadIdx.x >> 6, lane = threadIdx.x & 63;
  const int node = blockIdx.x*4 + wid;
  const int hh = lane >> 4;
  const int beg = ptr[node], deg = ptr[node+1] - beg;
  f32x4 ad4 = *(const f32x4*)(a_d + node*4);
  float acc[16], acc2[16];
  #pragma unroll
  for (int j=0;j<16;j++){ acc[j]=0.f; acc2[j]=0.f; }
  f32x4 denp = {0.f,0.f,0.f,0.f};
  const unsigned short* hb = h + lane*16;

  for (int c0 = 0; c0 < deg; c0 += 64){
    int n = min(64, deg - c0);
    if (lane < n){
      int s = csrc[beg + c0 + lane];
      f32x4 as4 = *(const f32x4*)(a_s + s*4);
      f32x4 e4;
      #pragma unroll
      for (int k2=0;k2<4;k2++){
        float ev = as4[k2] + ad4[k2];
        ev = ev > 0.f ? ev : 0.2f*ev;
        float x = __expf(ev);
        e4[k2] = x;
        denp[k2] += x;
      }
      *(f32x4*)&sal[wid][lane*4] = e4;
      ssn[wid][lane] = s;
    }
    int e = 0;
    for (; e + 1 < n; e += 2){
      int sA_ = ssn[wid][e], sB_ = ssn[wid][e+1];
      float aA = sal[wid][e*4 + hh], aB = sal[wid][(e+1)*4 + hh];
      const unsigned short* pA = hb + (size_t)sA_*1024;
      const unsigned short* pB = hb + (size_t)sB_*1024;
      short8 uA0 = *(const short8*)pA, uA1 = *(const short8*)(pA+8);
      short8 uB0 = *(const short8*)pB, uB1 = *(const short8*)(pB+8);
      #pragma unroll
      for (int j=0;j<8;j++){ acc[j]   += bf2f((unsigned short)uA0[j])*aA;
                             acc[8+j] += bf2f((unsigned short)uA1[j])*aA; }
      #pragma unroll
      for (int j=0;j<8;j++){ acc2[j]   += bf2f((unsigned short)uB0[j])*aB;
                             acc2[8+j] += bf2f((unsigned short)uB1[j])*aB; }
    }
    if (e < n){
      int sA_ = ssn[wid][e];
      float aA = sal[wid][e*4 + hh];
      const unsigned short* pA = hb + (size_t)sA_*1024;
      short8 uA0 = *(const short8*)pA, uA1 = *(const short8*)(pA+8);
      #pragma unroll
      for (int j=0;j<8;j++){ acc[j]   += bf2f((unsigned short)uA0[j])*aA;
                             acc[8+j] += bf2f((unsigned short)uA1[j])*aA; }
    }
  }
  #pragma unroll
  for (int o=32;o;o>>=1){
    #pragma unroll
    for (int k2=0;k2<4;k2++) denp[k2] += __shfl_xor(denp[k2], o);
  }
  float inv = 1.f / (denp[hh] + 1e-16f);
  float* op = out + (size_t)node*1024 + lane*16;
  const float* bp = bias + lane*16;
  #pragma unroll
  for (int j=0;j<16;j++) op[j] = (acc[j]+acc2[j])*inv + bp[j];
}

// ---------- fused softmax + gather, wave-per-node (layer 4: F=121, FS=128) ----------
__global__ __launch_bounds__(256) void k_gatherw1(
    const unsigned short* __restrict__ h,
    const float* __restrict__ a_s, const float* __restrict__ a_d,
    const int* __restrict__ ptr, const int* __restrict__ csrc,
    const float* __restrict__ bias, float* __restrict__ out)
{
  __shared__ float sal[4][64];
  __shared__ int ssn[4][64];
  const int wid = threadIdx.x >> 6, lane = threadIdx.x & 63;
  const int node = blockIdx.x*4 + wid;
  const int beg = ptr[node], deg = ptr[node+1] - beg;
  float ad = a_d[node];
  float den = 0.f;
  float acc[2] = {0.f,0.f}, acc2[2] = {0.f,0.f};
  const int c0i = lane*2;
  const unsigned short* hb = h + c0i;

  for (int b0 = 0; b0 < deg; b0 += 64){
    int n = min(64, deg - b0);
    if (lane < n){
      int s = csrc[beg + b0 + lane];
      float ev = a_s[s] + ad;
      ev = ev > 0.f ? ev : 0.2f*ev;
      float x = __expf(ev);
      sal[wid][lane] = x;
      ssn[wid][lane] = s;
      den += x;
    }
    int e = 0;
    for (; e + 1 < n; e += 2){
      int sA_ = ssn[wid][e], sB_ = ssn[wid][e+1];
      float aA = sal[wid][e], aB = sal[wid][e+1];
      const unsigned short* pA = hb + (size_t)sA_*128;
      const unsigned short* pB = hb + (size_t)sB_*128;
      acc[0]  += bf2f(pA[0])*aA; acc[1]  += bf2f(pA[1])*aA;
      acc2[0] += bf2f(pB[0])*aB; acc2[1] += bf2f(pB[1])*aB;
    }
    if (e < n){
      int sA_ = ssn[wid][e];
      float aA = sal[wid][e];
      const unsigned short* pA = hb + (size_t)sA_*128;
      acc[0] += bf2f(pA[0])*aA; acc[1] += bf2f(pA[1])*aA;
    }
  }
  #pragma unroll
  for (int o=32;o;o>>=1) den += __shfl_xor(den, o);
  float inv = 1.f / (den + 1e-16f);
  if (c0i < 121)   out[(size_t)node*121 + c0i]   = (acc[0]+acc2[0])*inv + bias[c0i];
  if (c0i+1 < 121) out[(size_t)node*121 + c0i+1] = (acc[1]+acc2[1])*inv + bias[c0i+1];
}

// ---------- GraphNorm stats (partials, no atomics) / coefs / apply+ELU ----------
__global__ void k_gnstats(const float* __restrict__ x, const int* __restrict__ gptr,
                          float* __restrict__ psum, float* __restrict__ psq){
  int g = blockIdx.x, cc = blockIdx.y, sp = blockIdx.z;
  int c = cc*256 + threadIdx.x;
  int beg = gptr[g], end = gptr[g+1];
  int n = end - beg;
  int per = (n + NSPLIT - 1) / NSPLIT;
  int nb = beg + sp*per, ne = min(end, nb + per);
  float s = 0.f, qv = 0.f;
  for (int i = nb; i < ne; i++){ float v = x[(size_t)i*1024 + c]; s += v; qv += v*v; }
  int idx = (sp*NG + g)*1024 + c;
  psum[idx] = s; psq[idx] = qv;
}

__global__ void k_coef(const float* __restrict__ psum, const float* __restrict__ psq,
                       const int* __restrict__ gptr,
                       const float* __restrict__ w, const float* __restrict__ b, const float* __restrict__ ms,
                       float* __restrict__ cA, float* __restrict__ cB){
  int i = blockIdx.x*256 + threadIdx.x;
  if (i >= NG*1024) return;
  int g = i >> 10, c = i & 1023;
  float cntf = (float)(gptr[g+1] - gptr[g]);
  float sm = 0.f, sq = 0.f;
  #pragma unroll
  for (int sp=0; sp<NSPLIT; sp++){
    sm += psum[(sp*NG + g)*1024 + c];
    sq += psq[(sp*NG + g)*1024 + c];
  }
  float m = sm / cntf;
  float s = ms[c];
  float ex2 = sq / cntf;
  float var = ex2 - 2.f*s*m*m + s*s*m*m;
  float inv = rsqrtf(var + 1e-5f);
  float wa = w[c]*inv;
  cA[i] = wa;
  cB[i] = b[c] - wa*m*s;
}

__global__ void k_applyelu(const float* __restrict__ x, const int* __restrict__ batch,
                           const float* __restrict__ cA, const float* __restrict__ cB,
                           unsigned short* __restrict__ obf){
  size_t i = (size_t)blockIdx.x*256 + threadIdx.x;
  if (i >= (size_t)NN*1024) return;
  int node = (int)(i >> 10);
  int c = (int)(i & 1023);
  int g = batch[node];
  float y = cA[g*1024 + c]*x[i] + cB[g*1024 + c];
  y = y > 0.f ? y : expm1f(y);
  obf[i] = f2bf(y);
}

// ---------- orchestration ----------
extern "C" void kernel_launch(void* const* d_in, const int* in_sizes, int n_in,
                              void* d_out, int out_size, void* d_ws, size_t ws_size,
                              hipStream_t stream){
  (void)in_sizes; (void)n_in; (void)out_size; (void)ws_size;
  const float* x     = (const float*)d_in[0];
  const int*   ei    = (const int*)d_in[1];
  const int*   batch = (const int*)d_in[2];
  const float* W[4]  = {(const float*)d_in[3],  (const float*)d_in[7],  (const float*)d_in[11], (const float*)d_in[15]};
  const float* AS[4] = {(const float*)d_in[4],  (const float*)d_in[8],  (const float*)d_in[12], (const float*)d_in[16]};
  const float* AD[4] = {(const float*)d_in[5],  (const float*)d_in[9],  (const float*)d_in[13], (const float*)d_in[17]};
  const float* BI[4] = {(const float*)d_in[6],  (const float*)d_in[10], (const float*)d_in[14], (const float*)d_in[18]};
  const float* GW[3] = {(const float*)d_in[19], (const float*)d_in[22], (const float*)d_in[25]};
  const float* GB[3] = {(const float*)d_in[20], (const float*)d_in[23], (const float*)d_in[26]};
  const float* GA[3] = {(const float*)d_in[21], (const float*)d_in[24], (const float*)d_in[27]};

  float* ws   = (float*)d_ws;
  float* bufB = ws;                                  // [NN,1024] f32
  float* a_s  = bufB + (size_t)NN*1024;              // [NN,4]
  float* a_d  = a_s + (size_t)NN*4;                  // [NN,4]
  float* psum = a_d + (size_t)NN*4;                  // [NSPLIT,NG,1024]
  float* psq  = psum + (size_t)NSPLIT*NG*1024;       // [NSPLIT,NG,1024]
  float* cA   = psq  + (size_t)NSPLIT*NG*1024;       // [NG,1024]
  float* cB   = cA   + (size_t)NG*1024;              // [NG,1024]
  int* ptr  = (int*)(cB + (size_t)NG*1024);          // [NN+1]
  int* fill = ptr + (NN + 8);                        // [NN+1]
  int* csrc = fill + (NN + 8);                       // [E2]
  int* gptr = csrc + E2;                             // [NG+1] (pad 24)
  unsigned short* abf = (unsigned short*)(gptr + 24);// [MPAD,1024] bf16 (xbf aliases start)
  unsigned short* xbf = abf;                         // [MPAD,64] bf16 (dead after L0 gemm)
  unsigned short* hbf = abf + (size_t)MPAD*1024;     // [NN,1024] bf16
  unsigned short* wt  = hbf + (size_t)NN*1024;       // [WTT] bf16 (all 4 layers)

  hipMemsetAsync(fill, 0, sizeof(int)*(NN+1), stream);
  k_gptr<<<1, 32, 0, stream>>>(batch, gptr);
  k_count<<<(E2+255)/256, 256, 0, stream>>>(ei, fill);
  k_scan<<<1, 256, 0, stream>>>(fill, ptr);
  k_copy<<<(NN+255)/256, 256, 0, stream>>>(ptr, fill);
  k_scatter<<<(E2+255)/256, 256, 0, stream>>>(ei, fill, csrc);
  k_xconv<<<(MPAD*64+255)/256, 256, 0, stream>>>(x, xbf);
  k_wconvall<<<(WTT+255)/256, 256, 0, stream>>>(W[0], W[1], W[2], W[3], wt);

  const int Kp[4]  = {64, 1024, 1024, 1024};
  const int Np[4]  = {1024, 1024, 1024, 128};
  const int Woff[4] = {WT0, WT1, WT2, WT3};
  for (int li = 0; li < 4; ++li){
    int FS = Np[li];
    const unsigned short* Ain = (li == 0) ? xbf : abf;
    const unsigned short* Wt = wt + Woff[li];
    if (li < 3){
      int ncb = Np[li]/128;                // 8
      int nwg = (MPAD/64) * ncb;           // 1264
      k_mfma_gemm<64,128><<<nwg, 256, 0, stream>>>(Ain, Wt, hbf, NN, Kp[li], FS, ncb);
      k_attprepw<<<NN/4, 256, 0, stream>>>(hbf, AS[li], AD[li], a_s, a_d);
      k_gatherw<<<NN/4, 256, 0, stream>>>(hbf, a_s, a_d, ptr, csrc, BI[li], bufB);
      k_gnstats<<<dim3(NG, 4, NSPLIT), 256, 0, stream>>>(bufB, gptr, psum, psq);
      k_coef<<<(NG*1024 + 255)/256, 256, 0, stream>>>(psum, psq, gptr, GW[li], GB[li], GA[li], cA, cB);
      k_applyelu<<<(NN*1024 + 255)/256, 256, 0, stream>>>(bufB, batch, cA, cB, abf);
    } else {
      int ncb = Np[li]/64;                 // 2
      int nwg = (MPAD/64) * ncb;           // 316
      k_mfma_gemm<64,64><<<nwg, 256, 0, stream>>>(Ain, Wt, hbf, NN, Kp[li], FS, ncb);
      k_attprep4<<<NN/4, 256, 0, stream>>>(hbf, AS[li], AD[li], a_s, a_d);
      k_gatherw1<<<NN/4, 256, 0, stream>>>(hbf, a_s, a_d, ptr, csrc, BI[li], (float*)d_out);
    }
  }
}

// Round 11
// 502.906 us; speedup vs baseline: 1.0951x; 1.0265x over previous
//
#include <hip/hip_runtime.h>
#include <math.h>

#define NN 10000
#define NE 160000
#define E2 (NE + NN)
#define NG 20
#define MPAD 10240   // 40 * 256
#define NSPLIT 8

typedef __attribute__((ext_vector_type(8))) short short8;
typedef __attribute__((ext_vector_type(4))) float f32x4;

// ---------- helpers ----------
__device__ inline unsigned short f2bf(float f){
  unsigned u = __float_as_uint(f);
  unsigned r = u + 0x7FFFu + ((u >> 16) & 1u);
  return (unsigned short)(r >> 16);
}
__device__ inline float bf2f(unsigned short h){ return __uint_as_float(((unsigned)h) << 16); }

__device__ inline void gload_lds16(const void* g, void* l){
  __builtin_amdgcn_global_load_lds((const __attribute__((address_space(1))) void*)g,
                                   (__attribute__((address_space(3))) void*)l, 16, 0, 0);
}

// ---------- graph boundary (batch is sorted) ----------
__global__ void k_gptr(const int* __restrict__ batch, int* __restrict__ gptr){
  int g = threadIdx.x;
  if (g > NG) return;
  int lo = 0, hi = NN;
  while (lo < hi){ int mid = (lo+hi)>>1; if (batch[mid] < g) lo = mid+1; else hi = mid; }
  gptr[g] = lo;
}

// ---------- CSR build (by dst, self-loops appended) ----------
__global__ void k_count(const int* __restrict__ ei, int* __restrict__ cnt){
  int e = blockIdx.x*256 + threadIdx.x;
  if (e >= E2) return;
  int d = (e < NE) ? ei[NE + e] : (e - NE);
  atomicAdd(&cnt[d], 1);
}

__global__ void k_scan(const int* __restrict__ cnt, int* __restrict__ ptr){
  __shared__ int tpre[256];
  __shared__ int tsum[256];
  int tid = threadIdx.x;
  const int per = (NN + 255)/256;
  int base = tid*per;
  int s = 0;
  for (int i=0;i<per;i++){ int idx=base+i; if (idx<NN) s += cnt[idx]; }
  tsum[tid] = s;
  __syncthreads();
  if (tid == 0){
    int run = 0;
    for (int i=0;i<256;i++){ tpre[i]=run; run += tsum[i]; }
    ptr[NN] = run;
  }
  __syncthreads();
  int run = tpre[tid];
  for (int i=0;i<per;i++){ int idx=base+i; if (idx<NN){ ptr[idx]=run; run += cnt[idx]; } }
}

__global__ void k_copy(const int* __restrict__ src, int* __restrict__ dst){
  int i = blockIdx.x*256 + threadIdx.x;
  if (i < NN) dst[i] = src[i];
}

__global__ void k_scatter(const int* __restrict__ ei, int* __restrict__ fill, int* __restrict__ csrc){
  int e = blockIdx.x*256 + threadIdx.x;
  if (e >= E2) return;
  int s, d;
  if (e < NE){ s = ei[e]; d = ei[NE + e]; } else { s = d = e - NE; }
  int pos = atomicAdd(&fill[d], 1);
  csrc[pos] = s;
}

// ---------- conversions ----------
__global__ void k_xconv(const float* __restrict__ x, unsigned short* __restrict__ xbf){
  int i = blockIdx.x*256 + threadIdx.x;
  if (i >= MPAD*64) return;
  int r = i >> 6, c = i & 63;
  float v = (r < NN && c < 50) ? x[r*50 + c] : 0.f;
  xbf[i] = f2bf(v);
}

// all four W -> transposed bf16 (zero-padded), single kernel
#define WT0 0
#define WT1 65536
#define WT2 1114112
#define WT3 2162688
#define WTT 2293760
__global__ void k_wconvall(const float* __restrict__ W0, const float* __restrict__ W1,
                           const float* __restrict__ W2, const float* __restrict__ W3,
                           unsigned short* __restrict__ wt){
  int i = blockIdx.x*256 + threadIdx.x;
  if (i >= WTT) return;
  const float* W; int K, N, Kpad, off;
  if (i < WT1){ W=W0; K=50; N=1024; Kpad=64; off=WT0; }
  else if (i < WT2){ W=W1; K=1024; N=1024; Kpad=1024; off=WT1; }
  else if (i < WT3){ W=W2; K=1024; N=1024; Kpad=1024; off=WT2; }
  else { W=W3; K=1024; N=121; Kpad=1024; off=WT3; }
  int j = i - off;
  int nn = j / Kpad, kk = j - nn*Kpad;
  float v = (nn < N && kk < K) ? W[(size_t)kk*N + nn] : 0.f;
  wt[i] = f2bf(v);
}

// ---------- bf16 MFMA GEMM: 256xTBN tile, 512 threads, <=1 block/CU ----------
// 8 waves (2 row x 4 col), wave tile 128 x TBN/4. 3-buffer LDS, one barrier
// per K-step, counted vmcnt. Chunk-swizzled LDS (both-sides XOR).
template<int TBN>
__global__ __launch_bounds__(512, 2) void k_gemm256(
    const unsigned short* __restrict__ A,
    const unsigned short* __restrict__ Bt,
    unsigned short* __restrict__ Cbf,
    int M, int K, int FS, int ncb)
{
  constexpr int MFR = 8;              // 128 rows / 16
  constexpr int NFR = TBN/64;         // wave cols (TBN/4) / 16
  constexpr int ABYTES = 256*64;      // 16 KB per K32 A-buffer
  constexpr int BBYTES = TBN*64;
  constexpr int AINST = 2;            // 1024 A-slots / 512 threads
  constexpr int BINST = TBN/128;
  constexpr int LPS = AINST + BINST;  // VMEM insts per wave per stage
  __shared__ unsigned short sA[3*256*32];
  __shared__ unsigned short sB[3*TBN*32];
  const int tid = threadIdx.x;
  const int wave = tid >> 6;
  const int lane = tid & 63;
  const int nwg = gridDim.x;
  const int q = nwg >> 3, rmod = nwg & 7;
  const int xcd = blockIdx.x & 7, idx = blockIdx.x >> 3;
  const int wg = (xcd < rmod) ? (xcd*(q+1) + idx) : (rmod*(q+1) + (xcd - rmod)*q + idx);
  const int rowt = wg / ncb;
  const int colt = wg - rowt*ncb;
  const int row0 = rowt * 256;
  const int col0 = colt * TBN;
  const int wr = (wave >> 2) * 128;
  const int wc = (wave & 3) * (TBN/4);
  f32x4 acc[MFR][NFR];
  #pragma unroll
  for (int i=0;i<MFR;i++)
    #pragma unroll
    for (int j=0;j<NFR;j++){ acc[i][j][0]=0.f; acc[i][j][1]=0.f; acc[i][j][2]=0.f; acc[i][j][3]=0.f; }

  // staging: inst i covers 64 consecutive slots; slot s -> (row=s>>2, chunk=s&3);
  // global source chunk XOR-swizzled, LDS stays linear (rule #21 both-sides).
  const unsigned short* aP[AINST];
  int aL[AINST];
  #pragma unroll
  for (int i=0;i<AINST;i++){
    int s = (wave*AINST + i)*64 + lane;
    int row = s >> 2, chn = (s & 3) ^ ((row >> 1) & 3);
    aP[i] = A + (size_t)(row0 + row)*K + chn*8;
    aL[i] = (wave*AINST + i)*1024;     // wave-uniform base (lane offset implicit)
  }
  const unsigned short* bP[BINST];
  int bL[BINST];
  #pragma unroll
  for (int i=0;i<BINST;i++){
    int s = (wave*BINST + i)*64 + lane;
    int row = s >> 2, chn = (s & 3) ^ ((row >> 1) & 3);
    bP[i] = Bt + (size_t)(col0 + row)*K + chn*8;
    bL[i] = (wave*BINST + i)*1024;
  }
  char* ldsA = (char*)sA;
  char* ldsB = (char*)sB;

  auto STAGE = [&](int k0, int buf){
    #pragma unroll
    for (int i=0;i<AINST;i++) gload_lds16(aP[i] + k0, ldsA + buf*ABYTES + aL[i]);
    #pragma unroll
    for (int i=0;i<BINST;i++) gload_lds16(bP[i] + k0, ldsB + buf*BBYTES + bL[i]);
  };

  const int NT = K >> 5;
  const int kch = lane >> 4;
  const int rlo = lane & 15;

  STAGE(0, 0);
  STAGE(32, 1);

  int cur = 0;
  for (int t = 0; t < NT; ++t){
    asm volatile("s_waitcnt lgkmcnt(0)" ::: "memory");
    if (t+1 < NT){
      if constexpr (LPS==4) asm volatile("s_waitcnt vmcnt(4)" ::: "memory");
      else                  asm volatile("s_waitcnt vmcnt(3)" ::: "memory");
    } else {
      asm volatile("s_waitcnt vmcnt(0)" ::: "memory");
    }
    __builtin_amdgcn_sched_barrier(0);
    __builtin_amdgcn_s_barrier();        // tile t resident; all t-1 reads retired
    __builtin_amdgcn_sched_barrier(0);
    const unsigned short* bA = sA + cur*(256*32);
    const unsigned short* bB = sB + cur*(TBN*32);
    short8 af[MFR], bfr[NFR];
    #pragma unroll
    for (int m=0;m<MFR;m++){
      int r = wr + m*16 + rlo;
      af[m] = *(const short8*)(bA + r*32 + ((kch ^ ((r>>1)&3))<<3));
    }
    #pragma unroll
    for (int n=0;n<NFR;n++){
      int r = wc + n*16 + rlo;
      bfr[n] = *(const short8*)(bB + r*32 + ((kch ^ ((r>>1)&3))<<3));
    }
    if (t+2 < NT){
      int nb = cur + 2; if (nb >= 3) nb -= 3;
      STAGE((t+2) << 5, nb);
    }
    __builtin_amdgcn_s_setprio(1);
    #pragma unroll
    for (int m=0;m<MFR;m++)
      #pragma unroll
      for (int n=0;n<NFR;n++)
        acc[m][n] = __builtin_amdgcn_mfma_f32_16x16x32_bf16(af[m], bfr[n], acc[m][n], 0, 0, 0);
    __builtin_amdgcn_s_setprio(0);
    cur += 1; if (cur == 3) cur = 0;
  }
  const int cr = (lane >> 4) * 4;
  const int cc = lane & 15;
  #pragma unroll
  for (int m=0;m<MFR;m++){
    #pragma unroll
    for (int n=0;n<NFR;n++){
      int col = col0 + wc + n*16 + cc;
      #pragma unroll
      for (int r=0;r<4;r++){
        int row = row0 + wr + m*16 + cr + r;
        if (row < M) Cbf[(size_t)row*FS + col] = f2bf(acc[m][n][r]);
      }
    }
  }
}

// ---------- wave-per-node attention halves (F=1024, H=4, FS=1024) ----------
__global__ __launch_bounds__(256) void k_attprepw(
    const unsigned short* __restrict__ h,
    const float* __restrict__ atts, const float* __restrict__ attd,
    float* __restrict__ a_s, float* __restrict__ a_d)
{
  const int wid = threadIdx.x >> 6, lane = threadIdx.x & 63;
  const int node = blockIdx.x*4 + wid;
  const unsigned short* hp = h + (size_t)node*1024 + lane*16;
  short8 v0 = *(const short8*)hp;
  short8 v1 = *(const short8*)(hp+8);
  const float* sp = atts + lane*16;
  const float* dp = attd + lane*16;
  float ss = 0.f, sd = 0.f;
  #pragma unroll
  for (int j=0;j<8;j++){ float f = bf2f((unsigned short)v0[j]); ss += f*sp[j];   sd += f*dp[j]; }
  #pragma unroll
  for (int j=0;j<8;j++){ float f = bf2f((unsigned short)v1[j]); ss += f*sp[8+j]; sd += f*dp[8+j]; }
  #pragma unroll
  for (int o=8;o;o>>=1){ ss += __shfl_xor(ss,o); sd += __shfl_xor(sd,o); }
  if ((lane & 15) == 0){
    int hh = lane >> 4;
    a_s[node*4 + hh] = ss;
    a_d[node*4 + hh] = sd;
  }
}

// ---------- wave-per-node attention halves (layer 4: F=121, FS=128, H=1) ----------
__global__ __launch_bounds__(256) void k_attprep4(
    const unsigned short* __restrict__ h,
    const float* __restrict__ atts, const float* __restrict__ attd,
    float* __restrict__ a_s, float* __restrict__ a_d)
{
  const int wid = threadIdx.x >> 6, lane = threadIdx.x & 63;
  const int node = blockIdx.x*4 + wid;
  const unsigned short* hp = h + (size_t)node*128;
  float ss = 0.f, sd = 0.f;
  {
    float f = bf2f(hp[lane]);
    if (lane < 121){ ss += f*atts[lane]; sd += f*attd[lane]; }
  }
  int c2 = lane + 64;
  if (c2 < 121){
    float f = bf2f(hp[c2]);
    ss += f*atts[c2]; sd += f*attd[c2];
  }
  #pragma unroll
  for (int o=32;o;o>>=1){ ss += __shfl_xor(ss,o); sd += __shfl_xor(sd,o); }
  if (lane == 0){ a_s[node] = ss; a_d[node] = sd; }
}

// ---------- fused softmax + gather, wave-per-node (F=1024, H=4, FS=1024) ----------
__global__ __launch_bounds__(256) void k_gatherw(
    const unsigned short* __restrict__ h,
    const float* __restrict__ a_s, const float* __restrict__ a_d,
    const int* __restrict__ ptr, const int* __restrict__ csrc,
    const float* __restrict__ bias, float* __restrict__ out)
{
  __shared__ float sal[4][64*4];
  __shared__ int ssn[4][64];
  const int wid = threadIdx.x >> 6, lane = threadIdx.x & 63;
  const int node = blockIdx.x*4 + wid;
  const int hh = lane >> 4;
  const int beg = ptr[node], deg = ptr[node+1] - beg;
  f32x4 ad4 = *(const f32x4*)(a_d + node*4);
  float acc[16], acc2[16];
  #pragma unroll
  for (int j=0;j<16;j++){ acc[j]=0.f; acc2[j]=0.f; }
  f32x4 denp = {0.f,0.f,0.f,0.f};
  const unsigned short* hb = h + lane*16;

  for (int c0 = 0; c0 < deg; c0 += 64){
    int n = min(64, deg - c0);
    if (lane < n){
      int s = csrc[beg + c0 + lane];
      f32x4 as4 = *(const f32x4*)(a_s + s*4);
      f32x4 e4;
      #pragma unroll
      for (int k2=0;k2<4;k2++){
        float ev = as4[k2] + ad4[k2];
        ev = ev > 0.f ? ev : 0.2f*ev;
        float x = __expf(ev);
        e4[k2] = x;
        denp[k2] += x;
      }
      *(f32x4*)&sal[wid][lane*4] = e4;
      ssn[wid][lane] = s;
    }
    int e = 0;
    for (; e + 1 < n; e += 2){
      int sA_ = ssn[wid][e], sB_ = ssn[wid][e+1];
      float aA = sal[wid][e*4 + hh], aB = sal[wid][(e+1)*4 + hh];
      const unsigned short* pA = hb + (size_t)sA_*1024;
      const unsigned short* pB = hb + (size_t)sB_*1024;
      short8 uA0 = *(const short8*)pA, uA1 = *(const short8*)(pA+8);
      short8 uB0 = *(const short8*)pB, uB1 = *(const short8*)(pB+8);
      #pragma unroll
      for (int j=0;j<8;j++){ acc[j]   += bf2f((unsigned short)uA0[j])*aA;
                             acc[8+j] += bf2f((unsigned short)uA1[j])*aA; }
      #pragma unroll
      for (int j=0;j<8;j++){ acc2[j]   += bf2f((unsigned short)uB0[j])*aB;
                             acc2[8+j] += bf2f((unsigned short)uB1[j])*aB; }
    }
    if (e < n){
      int sA_ = ssn[wid][e];
      float aA = sal[wid][e*4 + hh];
      const unsigned short* pA = hb + (size_t)sA_*1024;
      short8 uA0 = *(const short8*)pA, uA1 = *(const short8*)(pA+8);
      #pragma unroll
      for (int j=0;j<8;j++){ acc[j]   += bf2f((unsigned short)uA0[j])*aA;
                             acc[8+j] += bf2f((unsigned short)uA1[j])*aA; }
    }
  }
  #pragma unroll
  for (int o=32;o;o>>=1){
    #pragma unroll
    for (int k2=0;k2<4;k2++) denp[k2] += __shfl_xor(denp[k2], o);
  }
  float inv = 1.f / (denp[hh] + 1e-16f);
  float* op = out + (size_t)node*1024 + lane*16;
  const float* bp = bias + lane*16;
  #pragma unroll
  for (int j=0;j<16;j++) op[j] = (acc[j]+acc2[j])*inv + bp[j];
}

// ---------- fused softmax + gather, wave-per-node (layer 4: F=121, FS=128) ----------
__global__ __launch_bounds__(256) void k_gatherw1(
    const unsigned short* __restrict__ h,
    const float* __restrict__ a_s, const float* __restrict__ a_d,
    const int* __restrict__ ptr, const int* __restrict__ csrc,
    const float* __restrict__ bias, float* __restrict__ out)
{
  __shared__ float sal[4][64];
  __shared__ int ssn[4][64];
  const int wid = threadIdx.x >> 6, lane = threadIdx.x & 63;
  const int node = blockIdx.x*4 + wid;
  const int beg = ptr[node], deg = ptr[node+1] - beg;
  float ad = a_d[node];
  float den = 0.f;
  float acc[2] = {0.f,0.f}, acc2[2] = {0.f,0.f};
  const int c0i = lane*2;
  const unsigned short* hb = h + c0i;

  for (int b0 = 0; b0 < deg; b0 += 64){
    int n = min(64, deg - b0);
    if (lane < n){
      int s = csrc[beg + b0 + lane];
      float ev = a_s[s] + ad;
      ev = ev > 0.f ? ev : 0.2f*ev;
      float x = __expf(ev);
      sal[wid][lane] = x;
      ssn[wid][lane] = s;
      den += x;
    }
    int e = 0;
    for (; e + 1 < n; e += 2){
      int sA_ = ssn[wid][e], sB_ = ssn[wid][e+1];
      float aA = sal[wid][e], aB = sal[wid][e+1];
      const unsigned short* pA = hb + (size_t)sA_*128;
      const unsigned short* pB = hb + (size_t)sB_*128;
      acc[0]  += bf2f(pA[0])*aA; acc[1]  += bf2f(pA[1])*aA;
      acc2[0] += bf2f(pB[0])*aB; acc2[1] += bf2f(pB[1])*aB;
    }
    if (e < n){
      int sA_ = ssn[wid][e];
      float aA = sal[wid][e];
      const unsigned short* pA = hb + (size_t)sA_*128;
      acc[0] += bf2f(pA[0])*aA; acc[1] += bf2f(pA[1])*aA;
    }
  }
  #pragma unroll
  for (int o=32;o;o>>=1) den += __shfl_xor(den, o);
  float inv = 1.f / (den + 1e-16f);
  if (c0i < 121)   out[(size_t)node*121 + c0i]   = (acc[0]+acc2[0])*inv + bias[c0i];
  if (c0i+1 < 121) out[(size_t)node*121 + c0i+1] = (acc[1]+acc2[1])*inv + bias[c0i+1];
}

// ---------- GraphNorm stats (partials, no atomics) / coefs / apply+ELU ----------
__global__ void k_gnstats(const float* __restrict__ x, const int* __restrict__ gptr,
                          float* __restrict__ psum, float* __restrict__ psq){
  int g = blockIdx.x, cc = blockIdx.y, sp = blockIdx.z;
  int c = cc*256 + threadIdx.x;
  int beg = gptr[g], end = gptr[g+1];
  int n = end - beg;
  int per = (n + NSPLIT - 1) / NSPLIT;
  int nb = beg + sp*per, ne = min(end, nb + per);
  float s = 0.f, qv = 0.f;
  for (int i = nb; i < ne; i++){ float v = x[(size_t)i*1024 + c]; s += v; qv += v*v; }
  int idx = (sp*NG + g)*1024 + c;
  psum[idx] = s; psq[idx] = qv;
}

__global__ void k_coef(const float* __restrict__ psum, const float* __restrict__ psq,
                       const int* __restrict__ gptr,
                       const float* __restrict__ w, const float* __restrict__ b, const float* __restrict__ ms,
                       float* __restrict__ cA, float* __restrict__ cB){
  int i = blockIdx.x*256 + threadIdx.x;
  if (i >= NG*1024) return;
  int g = i >> 10, c = i & 1023;
  float cntf = (float)(gptr[g+1] - gptr[g]);
  float sm = 0.f, sq = 0.f;
  #pragma unroll
  for (int sp=0; sp<NSPLIT; sp++){
    sm += psum[(sp*NG + g)*1024 + c];
    sq += psq[(sp*NG + g)*1024 + c];
  }
  float m = sm / cntf;
  float s = ms[c];
  float ex2 = sq / cntf;
  float var = ex2 - 2.f*s*m*m + s*s*m*m;
  float inv = rsqrtf(var + 1e-5f);
  float wa = w[c]*inv;
  cA[i] = wa;
  cB[i] = b[c] - wa*m*s;
}

__global__ void k_applyelu(const float* __restrict__ x, const int* __restrict__ batch,
                           const float* __restrict__ cA, const float* __restrict__ cB,
                           unsigned short* __restrict__ obf){
  size_t i = (size_t)blockIdx.x*256 + threadIdx.x;
  if (i >= (size_t)NN*1024) return;
  int node = (int)(i >> 10);
  int c = (int)(i & 1023);
  int g = batch[node];
  float y = cA[g*1024 + c]*x[i] + cB[g*1024 + c];
  y = y > 0.f ? y : expm1f(y);
  obf[i] = f2bf(y);
}

// ---------- orchestration ----------
extern "C" void kernel_launch(void* const* d_in, const int* in_sizes, int n_in,
                              void* d_out, int out_size, void* d_ws, size_t ws_size,
                              hipStream_t stream){
  (void)in_sizes; (void)n_in; (void)out_size; (void)ws_size;
  const float* x     = (const float*)d_in[0];
  const int*   ei    = (const int*)d_in[1];
  const int*   batch = (const int*)d_in[2];
  const float* W[4]  = {(const float*)d_in[3],  (const float*)d_in[7],  (const float*)d_in[11], (const float*)d_in[15]};
  const float* AS[4] = {(const float*)d_in[4],  (const float*)d_in[8],  (const float*)d_in[12], (const float*)d_in[16]};
  const float* AD[4] = {(const float*)d_in[5],  (const float*)d_in[9],  (const float*)d_in[13], (const float*)d_in[17]};
  const float* BI[4] = {(const float*)d_in[6],  (const float*)d_in[10], (const float*)d_in[14], (const float*)d_in[18]};
  const float* GW[3] = {(const float*)d_in[19], (const float*)d_in[22], (const float*)d_in[25]};
  const float* GB[3] = {(const float*)d_in[20], (const float*)d_in[23], (const float*)d_in[26]};
  const float* GA[3] = {(const float*)d_in[21], (const float*)d_in[24], (const float*)d_in[27]};

  float* ws   = (float*)d_ws;
  float* bufB = ws;                                  // [NN,1024] f32
  float* a_s  = bufB + (size_t)NN*1024;              // [NN,4]
  float* a_d  = a_s + (size_t)NN*4;                  // [NN,4]
  float* psum = a_d + (size_t)NN*4;                  // [NSPLIT,NG,1024]
  float* psq  = psum + (size_t)NSPLIT*NG*1024;       // [NSPLIT,NG,1024]
  float* cA   = psq  + (size_t)NSPLIT*NG*1024;       // [NG,1024]
  float* cB   = cA   + (size_t)NG*1024;              // [NG,1024]
  int* ptr  = (int*)(cB + (size_t)NG*1024);          // [NN+1]
  int* fill = ptr + (NN + 8);                        // [NN+1]
  int* csrc = fill + (NN + 8);                       // [E2]
  int* gptr = csrc + E2;                             // [NG+1] (pad 24)
  unsigned short* abf = (unsigned short*)(gptr + 24);// [MPAD,1024] bf16 (xbf aliases start)
  unsigned short* xbf = abf;                         // [MPAD,64] bf16 (dead after L0 gemm)
  unsigned short* hbf = abf + (size_t)MPAD*1024;     // [NN,1024] bf16
  unsigned short* wt  = hbf + (size_t)NN*1024;       // [WTT] bf16 (all 4 layers)

  hipMemsetAsync(fill, 0, sizeof(int)*(NN+1), stream);
  k_gptr<<<1, 32, 0, stream>>>(batch, gptr);
  k_count<<<(E2+255)/256, 256, 0, stream>>>(ei, fill);
  k_scan<<<1, 256, 0, stream>>>(fill, ptr);
  k_copy<<<(NN+255)/256, 256, 0, stream>>>(ptr, fill);
  k_scatter<<<(E2+255)/256, 256, 0, stream>>>(ei, fill, csrc);
  k_xconv<<<(MPAD*64+255)/256, 256, 0, stream>>>(x, xbf);
  k_wconvall<<<(WTT+255)/256, 256, 0, stream>>>(W[0], W[1], W[2], W[3], wt);

  const int Kp[4]  = {64, 1024, 1024, 1024};
  const int Np[4]  = {1024, 1024, 1024, 128};
  const int Woff[4] = {WT0, WT1, WT2, WT3};
  for (int li = 0; li < 4; ++li){
    int FS = Np[li];
    const unsigned short* Ain = (li == 0) ? xbf : abf;
    const unsigned short* Wt = wt + Woff[li];
    if (li < 3){
      int ncb = 1024/256;                  // 4
      int nwg = (MPAD/256) * ncb;          // 40*4 = 160 blocks (<=1 per CU)
      k_gemm256<256><<<nwg, 512, 0, stream>>>(Ain, Wt, hbf, NN, Kp[li], FS, ncb);
      k_attprepw<<<NN/4, 256, 0, stream>>>(hbf, AS[li], AD[li], a_s, a_d);
      k_gatherw<<<NN/4, 256, 0, stream>>>(hbf, a_s, a_d, ptr, csrc, BI[li], bufB);
      k_gnstats<<<dim3(NG, 4, NSPLIT), 256, 0, stream>>>(bufB, gptr, psum, psq);
      k_coef<<<(NG*1024 + 255)/256, 256, 0, stream>>>(psum, psq, gptr, GW[li], GB[li], GA[li], cA, cB);
      k_applyelu<<<(NN*1024 + 255)/256, 256, 0, stream>>>(bufB, batch, cA, cB, abf);
    } else {
      int ncb = 1;                         // 128 cols = one col tile
      int nwg = (MPAD/256) * ncb;          // 40 blocks
      k_gemm256<128><<<nwg, 512, 0, stream>>>(Ain, Wt, hbf, NN, Kp[li], FS, ncb);
      k_attprep4<<<NN/4, 256, 0, stream>>>(hbf, AS[li], AD[li], a_s, a_d);
      k_gatherw1<<<NN/4, 256, 0, stream>>>(hbf, a_s, a_d, ptr, csrc, BI[li], (float*)d_out);
    }
  }
}

// Round 12
// 481.619 us; speedup vs baseline: 1.1435x; 1.0442x over previous
//
#include <hip/hip_runtime.h>
#include <math.h>

#define NN 10000
#define NE 160000
#define E2 (NE + NN)
#define NG 20
#define MPAD 10240   // 40 * 256
#define NSPLIT 8

typedef __attribute__((ext_vector_type(8))) short short8;
typedef __attribute__((ext_vector_type(4))) float f32x4;
typedef __attribute__((ext_vector_type(4))) unsigned short us4;

// ---------- helpers ----------
__device__ inline unsigned short f2bf(float f){
  unsigned u = __float_as_uint(f);
  unsigned r = u + 0x7FFFu + ((u >> 16) & 1u);
  return (unsigned short)(r >> 16);
}
__device__ inline float bf2f(unsigned short h){ return __uint_as_float(((unsigned)h) << 16); }

__device__ inline void gload_lds16(const void* g, void* l){
  __builtin_amdgcn_global_load_lds((const __attribute__((address_space(1))) void*)g,
                                   (__attribute__((address_space(3))) void*)l, 16, 0, 0);
}

// ---------- graph boundary (batch is sorted) ----------
__global__ void k_gptr(const int* __restrict__ batch, int* __restrict__ gptr){
  int g = threadIdx.x;
  if (g > NG) return;
  int lo = 0, hi = NN;
  while (lo < hi){ int mid = (lo+hi)>>1; if (batch[mid] < g) lo = mid+1; else hi = mid; }
  gptr[g] = lo;
}

// ---------- CSR build (by dst, self-loops appended) ----------
__global__ void k_count(const int* __restrict__ ei, int* __restrict__ cnt){
  int e = blockIdx.x*256 + threadIdx.x;
  if (e >= E2) return;
  int d = (e < NE) ? ei[NE + e] : (e - NE);
  atomicAdd(&cnt[d], 1);
}

__global__ void k_scan(const int* __restrict__ cnt, int* __restrict__ ptr){
  __shared__ int tpre[256];
  __shared__ int tsum[256];
  int tid = threadIdx.x;
  const int per = (NN + 255)/256;
  int base = tid*per;
  int s = 0;
  for (int i=0;i<per;i++){ int idx=base+i; if (idx<NN) s += cnt[idx]; }
  tsum[tid] = s;
  __syncthreads();
  if (tid == 0){
    int run = 0;
    for (int i=0;i<256;i++){ tpre[i]=run; run += tsum[i]; }
    ptr[NN] = run;
  }
  __syncthreads();
  int run = tpre[tid];
  for (int i=0;i<per;i++){ int idx=base+i; if (idx<NN){ ptr[idx]=run; run += cnt[idx]; } }
}

__global__ void k_copy(const int* __restrict__ src, int* __restrict__ dst){
  int i = blockIdx.x*256 + threadIdx.x;
  if (i < NN) dst[i] = src[i];
}

__global__ void k_scatter(const int* __restrict__ ei, int* __restrict__ fill, int* __restrict__ csrc){
  int e = blockIdx.x*256 + threadIdx.x;
  if (e >= E2) return;
  int s, d;
  if (e < NE){ s = ei[e]; d = ei[NE + e]; } else { s = d = e - NE; }
  int pos = atomicAdd(&fill[d], 1);
  csrc[pos] = s;
}

// ---------- conversions ----------
__global__ void k_xconv(const float* __restrict__ x, unsigned short* __restrict__ xbf){
  int i = blockIdx.x*256 + threadIdx.x;
  if (i >= MPAD*64) return;
  int r = i >> 6, c = i & 63;
  float v = (r < NN && c < 50) ? x[r*50 + c] : 0.f;
  xbf[i] = f2bf(v);
}

// all four W -> transposed bf16 (zero-padded), single kernel
#define WT0 0
#define WT1 65536
#define WT2 1114112
#define WT3 2162688
#define WTT 2293760
__global__ void k_wconvall(const float* __restrict__ W0, const float* __restrict__ W1,
                           const float* __restrict__ W2, const float* __restrict__ W3,
                           unsigned short* __restrict__ wt){
  int i = blockIdx.x*256 + threadIdx.x;
  if (i >= WTT) return;
  const float* W; int K, N, Kpad, off;
  if (i < WT1){ W=W0; K=50; N=1024; Kpad=64; off=WT0; }
  else if (i < WT2){ W=W1; K=1024; N=1024; Kpad=1024; off=WT1; }
  else if (i < WT3){ W=W2; K=1024; N=1024; Kpad=1024; off=WT2; }
  else { W=W3; K=1024; N=121; Kpad=1024; off=WT3; }
  int j = i - off;
  int nn = j / Kpad, kk = j - nn*Kpad;
  float v = (nn < N && kk < K) ? W[(size_t)kk*N + nn] : 0.f;
  wt[i] = f2bf(v);
}

// pad layer-4 att vectors 121 -> 128
__global__ void k_attpad4(const float* __restrict__ AS3, const float* __restrict__ AD3,
                          float* __restrict__ asp4, float* __restrict__ adp4){
  int i = threadIdx.x;   // 128
  asp4[i] = (i < 121) ? AS3[i] : 0.f;
  adp4[i] = (i < 121) ? AD3[i] : 0.f;
}

// ---------- bf16 MFMA GEMM: 256xTBN tile, 512 threads, <=1 block/CU ----------
// 8 waves (2 row x 4 col), wave tile 128 x TBN/4. 3-buffer LDS, one barrier
// per K-step, counted vmcnt, chunk-swizzled LDS. Epilogue computes the
// attention halves block-locally (col-tile == head width): shfl reduce over
// 16 lanes + LDS cross-wave reduce, NO atomics.
template<int TBN>
__global__ __launch_bounds__(512, 2) void k_gemm256(
    const unsigned short* __restrict__ A,
    const unsigned short* __restrict__ Bt,
    unsigned short* __restrict__ Cbf,
    const float* __restrict__ asp, const float* __restrict__ adp,
    float* __restrict__ a_s, float* __restrict__ a_d,
    int M, int K, int FS, int ncb, int H)
{
  constexpr int MFR = 8;
  constexpr int NFR = TBN/64;
  constexpr int ABYTES = 256*64;
  constexpr int BBYTES = TBN*64;
  constexpr int AINST = 2;
  constexpr int BINST = TBN/128;
  constexpr int LPS = AINST + BINST;
  __shared__ unsigned short sA[3*256*32];
  __shared__ unsigned short sB[3*TBN*32];
  const int tid = threadIdx.x;
  const int wave = tid >> 6;
  const int lane = tid & 63;
  const int nwg = gridDim.x;
  const int q = nwg >> 3, rmod = nwg & 7;
  const int xcd = blockIdx.x & 7, idx = blockIdx.x >> 3;
  const int wg = (xcd < rmod) ? (xcd*(q+1) + idx) : (rmod*(q+1) + (xcd - rmod)*q + idx);
  const int rowt = wg / ncb;
  const int colt = wg - rowt*ncb;
  const int row0 = rowt * 256;
  const int col0 = colt * TBN;
  const int wr = (wave >> 2) * 128;
  const int wc = (wave & 3) * (TBN/4);
  f32x4 acc[MFR][NFR];
  #pragma unroll
  for (int i=0;i<MFR;i++)
    #pragma unroll
    for (int j=0;j<NFR;j++){ acc[i][j][0]=0.f; acc[i][j][1]=0.f; acc[i][j][2]=0.f; acc[i][j][3]=0.f; }

  const unsigned short* aP[AINST];
  int aL[AINST];
  #pragma unroll
  for (int i=0;i<AINST;i++){
    int s = (wave*AINST + i)*64 + lane;
    int row = s >> 2, chn = (s & 3) ^ ((row >> 1) & 3);
    aP[i] = A + (size_t)(row0 + row)*K + chn*8;
    aL[i] = (wave*AINST + i)*1024;
  }
  const unsigned short* bP[BINST];
  int bL[BINST];
  #pragma unroll
  for (int i=0;i<BINST;i++){
    int s = (wave*BINST + i)*64 + lane;
    int row = s >> 2, chn = (s & 3) ^ ((row >> 1) & 3);
    bP[i] = Bt + (size_t)(col0 + row)*K + chn*8;
    bL[i] = (wave*BINST + i)*1024;
  }
  char* ldsA = (char*)sA;
  char* ldsB = (char*)sB;

  auto STAGE = [&](int k0, int buf){
    #pragma unroll
    for (int i=0;i<AINST;i++) gload_lds16(aP[i] + k0, ldsA + buf*ABYTES + aL[i]);
    #pragma unroll
    for (int i=0;i<BINST;i++) gload_lds16(bP[i] + k0, ldsB + buf*BBYTES + bL[i]);
  };

  const int NT = K >> 5;
  const int kch = lane >> 4;
  const int rlo = lane & 15;

  STAGE(0, 0);
  STAGE(32, 1);

  int cur = 0;
  for (int t = 0; t < NT; ++t){
    asm volatile("s_waitcnt lgkmcnt(0)" ::: "memory");
    if (t+1 < NT){
      if constexpr (LPS==4) asm volatile("s_waitcnt vmcnt(4)" ::: "memory");
      else                  asm volatile("s_waitcnt vmcnt(3)" ::: "memory");
    } else {
      asm volatile("s_waitcnt vmcnt(0)" ::: "memory");
    }
    __builtin_amdgcn_sched_barrier(0);
    __builtin_amdgcn_s_barrier();
    __builtin_amdgcn_sched_barrier(0);
    const unsigned short* bA = sA + cur*(256*32);
    const unsigned short* bB = sB + cur*(TBN*32);
    short8 af[MFR], bfr[NFR];
    #pragma unroll
    for (int m=0;m<MFR;m++){
      int r = wr + m*16 + rlo;
      af[m] = *(const short8*)(bA + r*32 + ((kch ^ ((r>>1)&3))<<3));
    }
    #pragma unroll
    for (int n=0;n<NFR;n++){
      int r = wc + n*16 + rlo;
      bfr[n] = *(const short8*)(bB + r*32 + ((kch ^ ((r>>1)&3))<<3));
    }
    if (t+2 < NT){
      int nb = cur + 2; if (nb >= 3) nb -= 3;
      STAGE((t+2) << 5, nb);
    }
    __builtin_amdgcn_s_setprio(1);
    #pragma unroll
    for (int m=0;m<MFR;m++)
      #pragma unroll
      for (int n=0;n<NFR;n++)
        acc[m][n] = __builtin_amdgcn_mfma_f32_16x16x32_bf16(af[m], bfr[n], acc[m][n], 0, 0, 0);
    __builtin_amdgcn_s_setprio(0);
    cur += 1; if (cur == 3) cur = 0;
  }
  const int cr = (lane >> 4) * 4;
  const int cc = lane & 15;
  // C store (bf16)
  #pragma unroll
  for (int m=0;m<MFR;m++){
    #pragma unroll
    for (int n=0;n<NFR;n++){
      int col = col0 + wc + n*16 + cc;
      #pragma unroll
      for (int r=0;r<4;r++){
        int row = row0 + wr + m*16 + cr + r;
        if (row < M) Cbf[(size_t)row*FS + col] = f2bf(acc[m][n][r]);
      }
    }
  }
  // fused attention halves: block-local (col-tile == full head)
  float asv[NFR], adv[NFR];
  #pragma unroll
  for (int n=0;n<NFR;n++){
    int col = col0 + wc + n*16 + cc;
    asv[n] = asp[col]; adv[n] = adp[col];
  }
  __syncthreads();                 // all waves done with LDS K-tiles
  float* part = (float*)sA;        // [2][128][4][2] = 8 KB
  #pragma unroll
  for (int m=0;m<MFR;m++){
    #pragma unroll
    for (int r=0;r<4;r++){
      float ss = 0.f, sd = 0.f;
      #pragma unroll
      for (int n=0;n<NFR;n++){ float v = acc[m][n][r]; ss += v*asv[n]; sd += v*adv[n]; }
      #pragma unroll
      for (int o=8;o;o>>=1){ ss += __shfl_xor(ss,o); sd += __shfl_xor(sd,o); }
      if (cc == 0){
        int rowLocal = m*16 + cr + r;
        int pidx = ((wave>>2)*128 + rowLocal)*8 + (wave&3)*2;
        part[pidx] = ss; part[pidx+1] = sd;
      }
    }
  }
  __syncthreads();
  {
    int row = tid >> 1, v = tid & 1;   // 512 threads = 256 rows x 2
    int base = row*8 + v;
    float s = part[base] + part[base+2] + part[base+4] + part[base+6];
    int grow = row0 + row;
    const int head = colt;
    if (grow < M){
      if (v) a_d[grow*H + head] = s;
      else   a_s[grow*H + head] = s;
    }
  }
}

// ---------- fused softmax + gather, wave-per-node (F=1024, H=4, FS=1024) ----------
// 2-edge ping-pong prefetch: next pair's 4x16B loads issued while FMA-ing
// current pair -> 8 loads in flight per lane.
__global__ __launch_bounds__(256) void k_gatherw(
    const unsigned short* __restrict__ h,
    const float* __restrict__ a_s, const float* __restrict__ a_d,
    const int* __restrict__ ptr, const int* __restrict__ csrc,
    const float* __restrict__ bias, float* __restrict__ out)
{
  __shared__ float sal[4][64*4];
  __shared__ int ssn[4][64];
  const int wid = threadIdx.x >> 6, lane = threadIdx.x & 63;
  const int node = blockIdx.x*4 + wid;
  const int hh = lane >> 4;
  const int beg = ptr[node], deg = ptr[node+1] - beg;
  f32x4 ad4 = *(const f32x4*)(a_d + node*4);
  float acc[16], acc2[16];
  #pragma unroll
  for (int j=0;j<16;j++){ acc[j]=0.f; acc2[j]=0.f; }
  f32x4 denp = {0.f,0.f,0.f,0.f};
  const unsigned short* hb = h + lane*16;

  for (int c0 = 0; c0 < deg; c0 += 64){
    int n = min(64, deg - c0);
    if (lane < n){
      int s = csrc[beg + c0 + lane];
      f32x4 as4 = *(const f32x4*)(a_s + s*4);
      f32x4 e4;
      #pragma unroll
      for (int k2=0;k2<4;k2++){
        float ev = as4[k2] + ad4[k2];
        ev = ev > 0.f ? ev : 0.2f*ev;
        float x = __expf(ev);
        e4[k2] = x;
        denp[k2] += x;
      }
      *(f32x4*)&sal[wid][lane*4] = e4;
      ssn[wid][lane] = s;
    }
    int e = 0;
    if (n >= 2){
      int s0 = ssn[wid][0], s1 = ssn[wid][1];
      float aA = sal[wid][hh], aB = sal[wid][4+hh];
      const unsigned short* p0 = hb + (size_t)s0*1024;
      const unsigned short* p1 = hb + (size_t)s1*1024;
      short8 ca0=*(const short8*)p0, ca1=*(const short8*)(p0+8);
      short8 cb0=*(const short8*)p1, cb1=*(const short8*)(p1+8);
      for (e = 0; e+3 < n; e += 2){
        int s2 = ssn[wid][e+2], s3 = ssn[wid][e+3];
        float nA = sal[wid][(e+2)*4+hh], nB = sal[wid][(e+3)*4+hh];
        const unsigned short* p2 = hb + (size_t)s2*1024;
        const unsigned short* p3 = hb + (size_t)s3*1024;
        short8 na0=*(const short8*)p2, na1=*(const short8*)(p2+8);
        short8 nb0=*(const short8*)p3, nb1=*(const short8*)(p3+8);
        #pragma unroll
        for (int j=0;j<8;j++){ acc[j]   += bf2f((unsigned short)ca0[j])*aA;
                               acc[8+j] += bf2f((unsigned short)ca1[j])*aA; }
        #pragma unroll
        for (int j=0;j<8;j++){ acc2[j]   += bf2f((unsigned short)cb0[j])*aB;
                               acc2[8+j] += bf2f((unsigned short)cb1[j])*aB; }
        ca0=na0; ca1=na1; cb0=nb0; cb1=nb1; aA=nA; aB=nB;
      }
      #pragma unroll
      for (int j=0;j<8;j++){ acc[j]   += bf2f((unsigned short)ca0[j])*aA;
                             acc[8+j] += bf2f((unsigned short)ca1[j])*aA; }
      #pragma unroll
      for (int j=0;j<8;j++){ acc2[j]   += bf2f((unsigned short)cb0[j])*aB;
                             acc2[8+j] += bf2f((unsigned short)cb1[j])*aB; }
      e += 2;
    }
    for (; e < n; ++e){
      int s = ssn[wid][e];
      float al = sal[wid][e*4 + hh];
      const unsigned short* p = hb + (size_t)s*1024;
      short8 u0 = *(const short8*)p, u1 = *(const short8*)(p+8);
      #pragma unroll
      for (int j=0;j<8;j++){ acc[j]   += bf2f((unsigned short)u0[j])*al;
                             acc[8+j] += bf2f((unsigned short)u1[j])*al; }
    }
  }
  #pragma unroll
  for (int o=32;o;o>>=1){
    #pragma unroll
    for (int k2=0;k2<4;k2++) denp[k2] += __shfl_xor(denp[k2], o);
  }
  float inv = 1.f / (denp[hh] + 1e-16f);
  float* op = out + (size_t)node*1024 + lane*16;
  const float* bp = bias + lane*16;
  #pragma unroll
  for (int j=0;j<16;j++) op[j] = (acc[j]+acc2[j])*inv + bp[j];
}

// ---------- fused softmax + gather, wave-per-node (layer 4: F=121, FS=128) ----------
__global__ __launch_bounds__(256) void k_gatherw1(
    const unsigned short* __restrict__ h,
    const float* __restrict__ a_s, const float* __restrict__ a_d,
    const int* __restrict__ ptr, const int* __restrict__ csrc,
    const float* __restrict__ bias, float* __restrict__ out)
{
  __shared__ float sal[4][64];
  __shared__ int ssn[4][64];
  const int wid = threadIdx.x >> 6, lane = threadIdx.x & 63;
  const int node = blockIdx.x*4 + wid;
  const int beg = ptr[node], deg = ptr[node+1] - beg;
  float ad = a_d[node];
  float den = 0.f;
  float acc[2] = {0.f,0.f}, acc2[2] = {0.f,0.f};
  const int c0i = lane*2;
  const unsigned short* hb = h + c0i;

  for (int b0 = 0; b0 < deg; b0 += 64){
    int n = min(64, deg - b0);
    if (lane < n){
      int s = csrc[beg + b0 + lane];
      float ev = a_s[s] + ad;
      ev = ev > 0.f ? ev : 0.2f*ev;
      float x = __expf(ev);
      sal[wid][lane] = x;
      ssn[wid][lane] = s;
      den += x;
    }
    int e = 0;
    for (; e + 1 < n; e += 2){
      int sA_ = ssn[wid][e], sB_ = ssn[wid][e+1];
      float aA = sal[wid][e], aB = sal[wid][e+1];
      const unsigned short* pA = hb + (size_t)sA_*128;
      const unsigned short* pB = hb + (size_t)sB_*128;
      acc[0]  += bf2f(pA[0])*aA; acc[1]  += bf2f(pA[1])*aA;
      acc2[0] += bf2f(pB[0])*aB; acc2[1] += bf2f(pB[1])*aB;
    }
    if (e < n){
      int sA_ = ssn[wid][e];
      float aA = sal[wid][e];
      const unsigned short* pA = hb + (size_t)sA_*128;
      acc[0] += bf2f(pA[0])*aA; acc[1] += bf2f(pA[1])*aA;
    }
  }
  #pragma unroll
  for (int o=32;o;o>>=1) den += __shfl_xor(den, o);
  float inv = 1.f / (den + 1e-16f);
  if (c0i < 121)   out[(size_t)node*121 + c0i]   = (acc[0]+acc2[0])*inv + bias[c0i];
  if (c0i+1 < 121) out[(size_t)node*121 + c0i+1] = (acc[1]+acc2[1])*inv + bias[c0i+1];
}

// ---------- GraphNorm stats (vectorized partials) / coefs / apply+ELU ----------
__global__ void k_gnstats(const float* __restrict__ x, const int* __restrict__ gptr,
                          float* __restrict__ psum, float* __restrict__ psq){
  int g = blockIdx.x, sp = blockIdx.z;
  int c4 = threadIdx.x*4;
  int beg = gptr[g], end = gptr[g+1];
  int n = end - beg;
  int per = (n + NSPLIT - 1) / NSPLIT;
  int nb = beg + sp*per, ne = min(end, nb + per);
  f32x4 s = {0.f,0.f,0.f,0.f}, qv = {0.f,0.f,0.f,0.f};
  for (int i = nb; i < ne; i++){
    f32x4 v = *(const f32x4*)(x + (size_t)i*1024 + c4);
    s += v; qv += v*v;
  }
  int idx = (sp*NG + g)*1024 + c4;
  *(f32x4*)(psum + idx) = s;
  *(f32x4*)(psq + idx) = qv;
}

__global__ void k_coef(const float* __restrict__ psum, const float* __restrict__ psq,
                       const int* __restrict__ gptr,
                       const float* __restrict__ w, const float* __restrict__ b, const float* __restrict__ ms,
                       float* __restrict__ cA, float* __restrict__ cB){
  int i = blockIdx.x*256 + threadIdx.x;
  if (i >= NG*1024) return;
  int g = i >> 10, c = i & 1023;
  float cntf = (float)(gptr[g+1] - gptr[g]);
  float sm = 0.f, sq = 0.f;
  #pragma unroll
  for (int sp=0; sp<NSPLIT; sp++){
    sm += psum[(sp*NG + g)*1024 + c];
    sq += psq[(sp*NG + g)*1024 + c];
  }
  float m = sm / cntf;
  float s = ms[c];
  float ex2 = sq / cntf;
  float var = ex2 - 2.f*s*m*m + s*s*m*m;
  float inv = rsqrtf(var + 1e-5f);
  float wa = w[c]*inv;
  cA[i] = wa;
  cB[i] = b[c] - wa*m*s;
}

__global__ void k_applyelu(const float* __restrict__ x, const int* __restrict__ batch,
                           const float* __restrict__ cA, const float* __restrict__ cB,
                           unsigned short* __restrict__ obf){
  int i = blockIdx.x*256 + threadIdx.x;        // over NN*256
  if (i >= NN*256) return;
  int node = i >> 8;
  int c4 = (i & 255)*4;
  int g = batch[node];
  f32x4 v = *(const f32x4*)(x + (size_t)node*1024 + c4);
  f32x4 a = *(const f32x4*)(cA + g*1024 + c4);
  f32x4 b = *(const f32x4*)(cB + g*1024 + c4);
  us4 o;
  #pragma unroll
  for (int j=0;j<4;j++){
    float y = a[j]*v[j] + b[j];
    y = y > 0.f ? y : expm1f(y);
    o[j] = f2bf(y);
  }
  *(us4*)(obf + (size_t)node*1024 + c4) = o;
}

// ---------- orchestration ----------
extern "C" void kernel_launch(void* const* d_in, const int* in_sizes, int n_in,
                              void* d_out, int out_size, void* d_ws, size_t ws_size,
                              hipStream_t stream){
  (void)in_sizes; (void)n_in; (void)out_size; (void)ws_size;
  const float* x     = (const float*)d_in[0];
  const int*   ei    = (const int*)d_in[1];
  const int*   batch = (const int*)d_in[2];
  const float* W[4]  = {(const float*)d_in[3],  (const float*)d_in[7],  (const float*)d_in[11], (const float*)d_in[15]};
  const float* AS[4] = {(const float*)d_in[4],  (const float*)d_in[8],  (const float*)d_in[12], (const float*)d_in[16]};
  const float* AD[4] = {(const float*)d_in[5],  (const float*)d_in[9],  (const float*)d_in[13], (const float*)d_in[17]};
  const float* BI[4] = {(const float*)d_in[6],  (const float*)d_in[10], (const float*)d_in[14], (const float*)d_in[18]};
  const float* GW[3] = {(const float*)d_in[19], (const float*)d_in[22], (const float*)d_in[25]};
  const float* GB[3] = {(const float*)d_in[20], (const float*)d_in[23], (const float*)d_in[26]};
  const float* GA[3] = {(const float*)d_in[21], (const float*)d_in[24], (const float*)d_in[27]};

  float* ws   = (float*)d_ws;
  float* bufB = ws;                                  // [NN,1024] f32
  float* a_s  = bufB + (size_t)NN*1024;              // [NN,4]
  float* a_d  = a_s + (size_t)NN*4;                  // [NN,4]
  float* psum = a_d + (size_t)NN*4;                  // [NSPLIT,NG,1024]
  float* psq  = psum + (size_t)NSPLIT*NG*1024;       // [NSPLIT,NG,1024]
  float* cA   = psq  + (size_t)NSPLIT*NG*1024;       // [NG,1024]
  float* cB   = cA   + (size_t)NG*1024;              // [NG,1024]
  float* asp4 = cB   + (size_t)NG*1024;              // [128]
  float* adp4 = asp4 + 128;                          // [128]
  int* ptr  = (int*)(adp4 + 128);                    // [NN+1]
  int* fill = ptr + (NN + 8);                        // [NN+1]
  int* csrc = fill + (NN + 8);                       // [E2]
  int* gptr = csrc + E2;                             // [NG+1] (pad 24)
  unsigned short* abf = (unsigned short*)(gptr + 24);// [MPAD,1024] bf16 (xbf aliases start)
  unsigned short* xbf = abf;                         // [MPAD,64] bf16 (dead after L0 gemm)
  unsigned short* hbf = abf + (size_t)MPAD*1024;     // [NN,1024] bf16
  unsigned short* wt  = hbf + (size_t)NN*1024;       // [WTT] bf16 (all 4 layers)

  hipMemsetAsync(fill, 0, sizeof(int)*(NN+1), stream);
  k_gptr<<<1, 32, 0, stream>>>(batch, gptr);
  k_count<<<(E2+255)/256, 256, 0, stream>>>(ei, fill);
  k_scan<<<1, 256, 0, stream>>>(fill, ptr);
  k_copy<<<(NN+255)/256, 256, 0, stream>>>(ptr, fill);
  k_scatter<<<(E2+255)/256, 256, 0, stream>>>(ei, fill, csrc);
  k_xconv<<<(MPAD*64+255)/256, 256, 0, stream>>>(x, xbf);
  k_wconvall<<<(WTT+255)/256, 256, 0, stream>>>(W[0], W[1], W[2], W[3], wt);
  k_attpad4<<<1, 128, 0, stream>>>(AS[3], AD[3], asp4, adp4);

  const int Kp[4]  = {64, 1024, 1024, 1024};
  const int Np[4]  = {1024, 1024, 1024, 128};
  const int Woff[4] = {WT0, WT1, WT2, WT3};
  for (int li = 0; li < 4; ++li){
    int FS = Np[li];
    const unsigned short* Ain = (li == 0) ? xbf : abf;
    const unsigned short* Wt = wt + Woff[li];
    if (li < 3){
      int ncb = 4;
      int nwg = (MPAD/256) * ncb;          // 160 blocks (<=1 per CU)
      k_gemm256<256><<<nwg, 512, 0, stream>>>(Ain, Wt, hbf, AS[li], AD[li], a_s, a_d,
                                              NN, Kp[li], FS, ncb, 4);
      k_gatherw<<<NN/4, 256, 0, stream>>>(hbf, a_s, a_d, ptr, csrc, BI[li], bufB);
      k_gnstats<<<dim3(NG, 1, NSPLIT), 256, 0, stream>>>(bufB, gptr, psum, psq);
      k_coef<<<(NG*1024 + 255)/256, 256, 0, stream>>>(psum, psq, gptr, GW[li], GB[li], GA[li], cA, cB);
      k_applyelu<<<(NN*256 + 255)/256, 256, 0, stream>>>(bufB, batch, cA, cB, abf);
    } else {
      int ncb = 1;
      int nwg = (MPAD/256) * ncb;          // 40 blocks
      k_gemm256<128><<<nwg, 512, 0, stream>>>(Ain, Wt, hbf, asp4, adp4, a_s, a_d,
                                              NN, Kp[li], FS, ncb, 1);
      k_gatherw1<<<NN/4, 256, 0, stream>>>(hbf, a_s, a_d, ptr, csrc, BI[li], (float*)d_out);
    }
  }
}